// Round 2
// baseline (137.826 us; speedup 1.0000x reference)
//
#include <hip/hip_runtime.h>
#include <math.h>

#define NTOK 2048
#define DMODEL 512
#define NH 8
#define HD 64
#define NF 128
#define QKV_LD 1536
#define CHUNK 64
#define NCHUNK 32
#define EPS_C 1e-8f

// ---------------- generic tiled fp32 GEMM: C = A@B (+bias) ----------------
// grid: (N/64, M/64), block 256, 4x4 micro-tile per thread, BK=16
template<bool BIAS>
__global__ __launch_bounds__(256) void gemm_tiled(
    const float* __restrict__ A, const float* __restrict__ B,
    const float* __restrict__ bias, float* __restrict__ C,
    int K, int lda, int ldb, int ldc)
{
  __shared__ float As[16][68];   // [k][m], padded stride 68 (16B aligned, bank-spread)
  __shared__ float Bs[16][64];   // [k][n]
  const int t = threadIdx.x;
  const int m0 = blockIdx.y * 64;
  const int n0 = blockIdx.x * 64;
  const int i0 = (t >> 4) * 4;
  const int j0 = (t & 15) * 4;
  const int ar = t >> 2;
  const int ac = (t & 3) * 4;
  const int br = t >> 4;
  const int bc = (t & 15) * 4;
  float acc[4][4] = {};
  for (int k0 = 0; k0 < K; k0 += 16) {
    const float4 a4 = *(const float4*)&A[(size_t)(m0 + ar) * lda + k0 + ac];
    const float4 b4 = *(const float4*)&B[(size_t)(k0 + br) * ldb + n0 + bc];
    As[ac + 0][ar] = a4.x;
    As[ac + 1][ar] = a4.y;
    As[ac + 2][ar] = a4.z;
    As[ac + 3][ar] = a4.w;
    *(float4*)&Bs[br][bc] = b4;
    __syncthreads();
#pragma unroll
    for (int kk = 0; kk < 16; ++kk) {
      const float4 av = *(const float4*)&As[kk][i0];
      const float4 bv = *(const float4*)&Bs[kk][j0];
      const float a_[4] = {av.x, av.y, av.z, av.w};
      const float b_[4] = {bv.x, bv.y, bv.z, bv.w};
#pragma unroll
      for (int i = 0; i < 4; ++i)
#pragma unroll
        for (int j = 0; j < 4; ++j)
          acc[i][j] = fmaf(a_[i], b_[j], acc[i][j]);
    }
    __syncthreads();
  }
#pragma unroll
  for (int i = 0; i < 4; ++i) {
    float4 o;
    o.x = acc[i][0]; o.y = acc[i][1]; o.z = acc[i][2]; o.w = acc[i][3];
    if (BIAS) {
      o.x += bias[n0 + j0 + 0];
      o.y += bias[n0 + j0 + 1];
      o.z += bias[n0 + j0 + 2];
      o.w += bias[n0 + j0 + 3];
    }
    *(float4*)&C[(size_t)(m0 + i0 + i) * ldc + n0 + j0] = o;
  }
}

// ---------------- projection GEMM + elu(x)+1 ----------------
// q_proj[h][n][f] = elu( sum_d qkv[n][src*512 + h*64 + d] * proj[h][d][f] ) + 1
// grid: (M/64=32, src*2+ntile=4, h=8)
__global__ __launch_bounds__(256) void proj_gemm(
    const float* __restrict__ qkv, const float* __restrict__ proj,
    float* __restrict__ q_proj, float* __restrict__ k_proj)
{
  __shared__ float As[16][68];
  __shared__ float Bs[16][64];
  const int t = threadIdx.x;
  const int h = blockIdx.z;
  const int src = blockIdx.y >> 1;
  const int n0 = (blockIdx.y & 1) * 64;
  const int m0 = blockIdx.x * 64;
  const float* A = qkv + src * DMODEL + h * HD;     // lda = QKV_LD, K = 64
  const float* B = proj + (size_t)h * HD * NF;      // ldb = NF
  float* C = (src ? k_proj : q_proj) + (size_t)h * NTOK * NF;
  const int i0 = (t >> 4) * 4;
  const int j0 = (t & 15) * 4;
  const int ar = t >> 2;
  const int ac = (t & 3) * 4;
  const int br = t >> 4;
  const int bc = (t & 15) * 4;
  float acc[4][4] = {};
  for (int k0 = 0; k0 < HD; k0 += 16) {
    const float4 a4 = *(const float4*)&A[(size_t)(m0 + ar) * QKV_LD + k0 + ac];
    const float4 b4 = *(const float4*)&B[(size_t)(k0 + br) * NF + n0 + bc];
    As[ac + 0][ar] = a4.x;
    As[ac + 1][ar] = a4.y;
    As[ac + 2][ar] = a4.z;
    As[ac + 3][ar] = a4.w;
    *(float4*)&Bs[br][bc] = b4;
    __syncthreads();
#pragma unroll
    for (int kk = 0; kk < 16; ++kk) {
      const float4 av = *(const float4*)&As[kk][i0];
      const float4 bv = *(const float4*)&Bs[kk][j0];
      const float a_[4] = {av.x, av.y, av.z, av.w};
      const float b_[4] = {bv.x, bv.y, bv.z, bv.w};
#pragma unroll
      for (int i = 0; i < 4; ++i)
#pragma unroll
        for (int j = 0; j < 4; ++j)
          acc[i][j] = fmaf(a_[i], b_[j], acc[i][j]);
    }
    __syncthreads();
  }
#pragma unroll
  for (int i = 0; i < 4; ++i) {
    float4 o;
    // elu(v)+1 == v+1 (v>0) else exp(v)
    o.x = acc[i][0] > 0.f ? acc[i][0] + 1.f : expf(acc[i][0]);
    o.y = acc[i][1] > 0.f ? acc[i][1] + 1.f : expf(acc[i][1]);
    o.z = acc[i][2] > 0.f ? acc[i][2] + 1.f : expf(acc[i][2]);
    o.w = acc[i][3] > 0.f ? acc[i][3] + 1.f : expf(acc[i][3]);
    *(float4*)&C[(size_t)(m0 + i0 + i) * NF + n0 + j0] = o;
  }
}

// ---------------- per-chunk K^T V sums (and K column sums) ----------------
// grid: (NCHUNK, NH), block 256
__global__ __launch_bounds__(256) void chunk_sums(
    const float* __restrict__ qkv, const float* __restrict__ k_proj,
    float* __restrict__ kvsum, float* __restrict__ ksum)
{
  __shared__ float Kp[CHUNK][NF];     // 32 KB
  __shared__ float Vs[CHUNK][HD];     // 16 KB
  const int c = blockIdx.x, h = blockIdx.y;
  const int t = threadIdx.x;
  const float* kp_base = k_proj + ((size_t)h * NTOK + c * CHUNK) * NF;
  const float* v_base  = qkv + (size_t)(c * CHUNK) * QKV_LD + 2 * DMODEL + h * HD;
  for (int idx = t; idx < CHUNK * 32; idx += 256) {
    const int r = idx >> 5, c4 = (idx & 31) * 4;
    *(float4*)&Kp[r][c4] = *(const float4*)&kp_base[r * NF + c4];
  }
  for (int idx = t; idx < CHUNK * 16; idx += 256) {
    const int r = idx >> 4, c4 = (idx & 15) * 4;
    *(float4*)&Vs[r][c4] = *(const float4*)&v_base[(size_t)r * QKV_LD + c4];
  }
  __syncthreads();
  const int f0 = (t & 31) * 4;   // 4 features
  const int d0 = (t >> 5) * 8;   // 8 dims
  float acc[4][8] = {};
  for (int j = 0; j < CHUNK; ++j) {
    const float4 kv = *(const float4*)&Kp[j][f0];
    const float k_[4] = {kv.x, kv.y, kv.z, kv.w};
    const float4 v0 = *(const float4*)&Vs[j][d0];
    const float4 v1 = *(const float4*)&Vs[j][d0 + 4];
    const float v_[8] = {v0.x, v0.y, v0.z, v0.w, v1.x, v1.y, v1.z, v1.w};
#pragma unroll
    for (int i = 0; i < 4; ++i)
#pragma unroll
      for (int jj = 0; jj < 8; ++jj)
        acc[i][jj] = fmaf(k_[i], v_[jj], acc[i][jj]);
  }
  float* outp = kvsum + ((size_t)h * NCHUNK + c) * NF * HD;
#pragma unroll
  for (int i = 0; i < 4; ++i) {
    float4 r0, r1;
    r0.x = acc[i][0]; r0.y = acc[i][1]; r0.z = acc[i][2]; r0.w = acc[i][3];
    r1.x = acc[i][4]; r1.y = acc[i][5]; r1.z = acc[i][6]; r1.w = acc[i][7];
    *(float4*)&outp[(f0 + i) * HD + d0]     = r0;
    *(float4*)&outp[(f0 + i) * HD + d0 + 4] = r1;
  }
  if (t < 32) {
#pragma unroll
    for (int q = 0; q < 4; ++q) {
      const int f = t * 4 + q;
      float s = 0.f;
      for (int j = 0; j < CHUNK; ++j) s += Kp[j][f];
      ksum[((size_t)h * NCHUNK + c) * NF + f] = s;
    }
  }
}

// ---------------- in-place exclusive prefix over chunks ----------------
// grid: (NCHUNK + 1, NH), block 256
__global__ __launch_bounds__(256) void chunk_scan(
    float* __restrict__ kvsum, float* __restrict__ ksum)
{
  const int h = blockIdx.y;
  const int t = threadIdx.x;
  if (blockIdx.x < NCHUNK) {
    const int e = blockIdx.x * 256 + t;   // 0..8191
    const size_t base = (size_t)h * NCHUNK * NF * HD + e;
    float run = 0.f;
    for (int c = 0; c < NCHUNK; ++c) {
      const size_t idx = base + (size_t)c * NF * HD;
      const float v = kvsum[idx];
      kvsum[idx] = run;
      run += v;
    }
  } else if (t < NF) {
    const size_t base = (size_t)h * NCHUNK * NF + t;
    float run = 0.f;
    for (int c = 0; c < NCHUNK; ++c) {
      const size_t idx = base + (size_t)c * NF;
      const float v = ksum[idx];
      ksum[idx] = run;
      run += v;
    }
  }
}

// ---------------- per-chunk attention: inter + masked intra + denom ----------------
// grid: (NCHUNK, NH), block 256
__global__ __launch_bounds__(256) void chunk_attn(
    const float* __restrict__ qkv, const float* __restrict__ q_proj,
    const float* __restrict__ k_proj, const float* __restrict__ kvpre,
    const float* __restrict__ kpre, float* __restrict__ attn)
{
  __shared__ float Qph[CHUNK][68];   // 17 KB : Q-proj half (f-slice)
  __shared__ float Kph[CHUNK][68];   // 17 KB : K-proj half, later reused for V
  __shared__ float Sb[CHUNK][68];    // 17 KB : KV-prefix half during passes, then S
  __shared__ float den[CHUNK];
  const int c = blockIdx.x, h = blockIdx.y;
  const int t = threadIdx.x;
  const int i0 = (t >> 4) * 4;   // output rows
  const int j0 = (t & 15) * 4;   // output cols (S-col tile == d tile)
  const float* qp_base   = q_proj + ((size_t)h * NTOK + c * CHUNK) * NF;
  const float* kp_base   = k_proj + ((size_t)h * NTOK + c * CHUNK) * NF;
  const float* kvp_base  = kvpre + ((size_t)h * NCHUNK + c) * NF * HD;
  const float* kpre_base = kpre + ((size_t)h * NCHUNK + c) * NF;
  float s_[4][4] = {};
  float o_[4][4] = {};
  float pd = 0.f;
#pragma unroll
  for (int p = 0; p < 2; ++p) {
    for (int idx = t; idx < CHUNK * 16; idx += 256) {
      const int r = idx >> 4, c4 = (idx & 15) * 4;
      *(float4*)&Qph[r][c4] = *(const float4*)&qp_base[r * NF + p * 64 + c4];
      *(float4*)&Kph[r][c4] = *(const float4*)&kp_base[r * NF + p * 64 + c4];
      *(float4*)&Sb[r][c4]  = *(const float4*)&kvp_base[(p * 64 + r) * HD + c4];
    }
    __syncthreads();
#pragma unroll 4
    for (int f = 0; f < 64; f += 4) {
      float q_[4][4], k_[4][4];
#pragma unroll
      for (int i = 0; i < 4; ++i) {
        const float4 qa = *(const float4*)&Qph[i0 + i][f];
        q_[i][0] = qa.x; q_[i][1] = qa.y; q_[i][2] = qa.z; q_[i][3] = qa.w;
        const float4 kb = *(const float4*)&Kph[j0 + i][f];
        k_[i][0] = kb.x; k_[i][1] = kb.y; k_[i][2] = kb.z; k_[i][3] = kb.w;
      }
#pragma unroll
      for (int i = 0; i < 4; ++i)
#pragma unroll
        for (int j = 0; j < 4; ++j)
          s_[i][j] += q_[i][0] * k_[j][0] + q_[i][1] * k_[j][1]
                    + q_[i][2] * k_[j][2] + q_[i][3] * k_[j][3];
#pragma unroll
      for (int ff = 0; ff < 4; ++ff) {
        const float4 pv = *(const float4*)&Sb[f + ff][j0];
#pragma unroll
        for (int i = 0; i < 4; ++i) {
          o_[i][0] = fmaf(q_[i][ff], pv.x, o_[i][0]);
          o_[i][1] = fmaf(q_[i][ff], pv.y, o_[i][1]);
          o_[i][2] = fmaf(q_[i][ff], pv.z, o_[i][2]);
          o_[i][3] = fmaf(q_[i][ff], pv.w, o_[i][3]);
        }
      }
    }
    if (t < CHUNK) {
#pragma unroll 8
      for (int f = 0; f < 64; ++f)
        pd = fmaf(Qph[t][f], kpre_base[p * 64 + f], pd);
    }
    __syncthreads();
  }
  // write S into Sb; stage V into Kph (both buffers free now)
#pragma unroll
  for (int i = 0; i < 4; ++i)
#pragma unroll
    for (int j = 0; j < 4; ++j)
      Sb[i0 + i][j0 + j] = s_[i][j];
  const float* v_base = qkv + (size_t)(c * CHUNK) * QKV_LD + 2 * DMODEL + h * HD;
  for (int idx = t; idx < CHUNK * 16; idx += 256) {
    const int r = idx >> 4, c4 = (idx & 15) * 4;
    *(float4*)&Kph[r][c4] = *(const float4*)&v_base[(size_t)r * QKV_LD + c4];
  }
  __syncthreads();
  if (t < CHUNK) {
    float rs = 0.f;
    for (int j = 0; j <= t; ++j) rs += Sb[t][j];
    den[t] = pd + rs + EPS_C;
  }
  __syncthreads();
  // intra: o += tril(S) @ V
  for (int j = 0; j < CHUNK; ++j) {
    const float4 vv = *(const float4*)&Kph[j][j0];
#pragma unroll
    for (int i = 0; i < 4; ++i) {
      const float sj = (j <= i0 + i) ? Sb[i0 + i][j] : 0.f;
      o_[i][0] = fmaf(sj, vv.x, o_[i][0]);
      o_[i][1] = fmaf(sj, vv.y, o_[i][1]);
      o_[i][2] = fmaf(sj, vv.z, o_[i][2]);
      o_[i][3] = fmaf(sj, vv.w, o_[i][3]);
    }
  }
#pragma unroll
  for (int i = 0; i < 4; ++i) {
    const float dinv = 1.0f / den[i0 + i];
    float4 r;
    r.x = o_[i][0] * dinv; r.y = o_[i][1] * dinv;
    r.z = o_[i][2] * dinv; r.w = o_[i][3] * dinv;
    *(float4*)&attn[(size_t)(c * CHUNK + i0 + i) * DMODEL + h * HD + j0] = r;
  }
}

extern "C" void kernel_launch(void* const* d_in, const int* in_sizes, int n_in,
                              void* d_out, int out_size, void* d_ws, size_t ws_size,
                              hipStream_t stream) {
  const float* x     = (const float*)d_in[0];
  const float* proj  = (const float*)d_in[1];
  const float* W_qkv = (const float*)d_in[2];
  const float* W_out = (const float*)d_in[3];
  const float* b_out = (const float*)d_in[4];
  float* out = (float*)d_out;
  float* ws = (float*)d_ws;

  float* qkv    = ws;                              // 2048*1536      = 3,145,728
  float* q_proj = qkv    + (size_t)NTOK * QKV_LD;  // 8*2048*128     = 2,097,152
  float* k_proj = q_proj + (size_t)NH * NTOK * NF; // 2,097,152
  float* kvsum  = k_proj + (size_t)NH * NTOK * NF; // 8*32*128*64    = 2,097,152
  float* ksum   = kvsum  + (size_t)NH * NCHUNK * NF * HD; // 8*32*128 = 32,768
  float* attn   = ksum   + (size_t)NH * NCHUNK * NF;      // 2048*512 = 1,048,576
  // total ws: ~42 MB of floats

  // 1) qkv = x @ W_qkv            (2048 x 1536 x 512)  A row-stride = DMODEL!
  gemm_tiled<false><<<dim3(QKV_LD / 64, NTOK / 64), 256, 0, stream>>>(
      x, W_qkv, nullptr, qkv, DMODEL, DMODEL, QKV_LD, QKV_LD);
  // 2) q_proj/k_proj = elu(head-GEMM)+1
  proj_gemm<<<dim3(NTOK / 64, 4, NH), 256, 0, stream>>>(qkv, proj, q_proj, k_proj);
  // 3) per-chunk K^T V and K sums
  chunk_sums<<<dim3(NCHUNK, NH), 256, 0, stream>>>(qkv, k_proj, kvsum, ksum);
  // 4) exclusive prefix over chunks (in place)
  chunk_scan<<<dim3(NCHUNK + 1, NH), 256, 0, stream>>>(kvsum, ksum);
  // 5) per-chunk attention
  chunk_attn<<<dim3(NCHUNK, NH), 256, 0, stream>>>(qkv, q_proj, k_proj, kvsum, ksum, attn);
  // 6) out = attn @ W_out + b_out (2048 x 512 x 512)
  gemm_tiled<true><<<dim3(DMODEL / 64, NTOK / 64), 256, 0, stream>>>(
      attn, W_out, b_out, out, DMODEL, DMODEL, DMODEL, DMODEL);
}

// Round 3
// 104.927 us; speedup vs baseline: 1.3135x; 1.3135x over previous
//
#include <hip/hip_runtime.h>
#include <math.h>

#define NTOK 2048
#define DMODEL 512
#define NH 8
#define HD 64
#define NF 128
#define QKV_LD 1536
#define CHUNK 64
#define NCHUNK 32
#define EPS_C 1e-8f

typedef __bf16 bf16x8 __attribute__((ext_vector_type(8)));
typedef float f32x4 __attribute__((ext_vector_type(4)));

__device__ inline unsigned short f2bf(float f) {
  union { float f; unsigned u; } v; v.f = f;
  unsigned r = v.u + 0x7FFF + ((v.u >> 16) & 1);   // round-to-nearest-even
  return (unsigned short)(r >> 16);
}

// ---------------- fp32 -> bf16 elementwise ----------------
__global__ __launch_bounds__(256) void cvt_bf16(
    const float* __restrict__ in, unsigned short* __restrict__ out, int n)
{
  const int i = (blockIdx.x * 256 + threadIdx.x) * 4;
  if (i < n) {
    const float4 v = *(const float4*)&in[i];
    ushort4 o;
    o.x = f2bf(v.x); o.y = f2bf(v.y); o.z = f2bf(v.z); o.w = f2bf(v.w);
    *(ushort4*)&out[i] = o;
  }
}

// ---------------- fp32 [R][C] -> bf16 transposed [C][R] ----------------
__global__ __launch_bounds__(256) void cvt_T(
    const float* __restrict__ in, unsigned short* __restrict__ out, int R, int C)
{
  __shared__ float T[32][33];
  const int c0 = blockIdx.x * 32, r0 = blockIdx.y * 32;
  const int tx = threadIdx.x & 31, ty = threadIdx.x >> 5;   // ty 0..7
#pragma unroll
  for (int i = 0; i < 32; i += 8)
    T[ty + i][tx] = in[(size_t)(r0 + ty + i) * C + c0 + tx];
  __syncthreads();
#pragma unroll
  for (int i = 0; i < 32; i += 8)
    out[(size_t)(c0 + ty + i) * R + r0 + tx] = f2bf(T[tx][ty + i]);
}

// ---------------- bf16 MFMA GEMM: C(f32) = A(bf16) @ Bt(bf16)^T (+bias) ----
// A: M x K row-major. Bt: N x K row-major (B transposed). 64x64 tile, 4 waves,
// each wave 32x32 via 2x2 mfma_f32_16x16x32_bf16. Fragments straight from
// global (operands are L2-resident; per-row 64B segments, fully-used lines).
template<bool BIAS>
__global__ __launch_bounds__(256) void gemm_mfma(
    const unsigned short* __restrict__ A, const unsigned short* __restrict__ Bt,
    const float* __restrict__ bias, float* __restrict__ C, int K, int ldc)
{
  const int t = threadIdx.x;
  const int lane = t & 63, w = t >> 6;
  const int wr = w >> 1, wc = w & 1;
  const int r16 = lane & 15, kg = lane >> 4;
  const int m0 = blockIdx.y * 64 + wr * 32;
  const int n0 = blockIdx.x * 64 + wc * 32;
  const unsigned short* a0 = A + (size_t)(m0 + r16) * K + kg * 8;
  const unsigned short* a1 = a0 + (size_t)16 * K;
  const unsigned short* b0 = Bt + (size_t)(n0 + r16) * K + kg * 8;
  const unsigned short* b1 = b0 + (size_t)16 * K;
  f32x4 acc00 = {0.f, 0.f, 0.f, 0.f}, acc01 = acc00, acc10 = acc00, acc11 = acc00;
#pragma unroll 4
  for (int k0 = 0; k0 < K; k0 += 32) {
    const bf16x8 af0 = *(const bf16x8*)(a0 + k0);
    const bf16x8 af1 = *(const bf16x8*)(a1 + k0);
    const bf16x8 bv0 = *(const bf16x8*)(b0 + k0);
    const bf16x8 bv1 = *(const bf16x8*)(b1 + k0);
    acc00 = __builtin_amdgcn_mfma_f32_16x16x32_bf16(af0, bv0, acc00, 0, 0, 0);
    acc01 = __builtin_amdgcn_mfma_f32_16x16x32_bf16(af0, bv1, acc01, 0, 0, 0);
    acc10 = __builtin_amdgcn_mfma_f32_16x16x32_bf16(af1, bv0, acc10, 0, 0, 0);
    acc11 = __builtin_amdgcn_mfma_f32_16x16x32_bf16(af1, bv1, acc11, 0, 0, 0);
  }
  // D layout (m89-verified): col = lane&15, row = (lane>>4)*4 + reg
  const int drow = kg * 4, dcol = r16;
#pragma unroll
  for (int mb = 0; mb < 2; ++mb) {
#pragma unroll
    for (int nb = 0; nb < 2; ++nb) {
      const f32x4 a = mb == 0 ? (nb == 0 ? acc00 : acc01) : (nb == 0 ? acc10 : acc11);
      const int col = n0 + nb * 16 + dcol;
      const float bv = BIAS ? bias[col] : 0.f;
#pragma unroll
      for (int r = 0; r < 4; ++r)
        C[(size_t)(m0 + mb * 16 + drow + r) * ldc + col] = a[r] + bv;
    }
  }
}

// ---------------- projection GEMM + elu(x)+1 ----------------
__global__ __launch_bounds__(256) void proj_gemm(
    const float* __restrict__ qkv, const float* __restrict__ proj,
    float* __restrict__ q_proj, float* __restrict__ k_proj)
{
  __shared__ float As[16][68];
  __shared__ float Bs[16][64];
  const int t = threadIdx.x;
  const int h = blockIdx.z;
  const int src = blockIdx.y >> 1;
  const int n0 = (blockIdx.y & 1) * 64;
  const int m0 = blockIdx.x * 64;
  const float* A = qkv + src * DMODEL + h * HD;     // lda = QKV_LD, K = 64
  const float* B = proj + (size_t)h * HD * NF;      // ldb = NF
  float* C = (src ? k_proj : q_proj) + (size_t)h * NTOK * NF;
  const int i0 = (t >> 4) * 4;
  const int j0 = (t & 15) * 4;
  const int ar = t >> 2;
  const int ac = (t & 3) * 4;
  const int br = t >> 4;
  const int bc = (t & 15) * 4;
  float acc[4][4] = {};
  for (int k0 = 0; k0 < HD; k0 += 16) {
    const float4 a4 = *(const float4*)&A[(size_t)(m0 + ar) * QKV_LD + k0 + ac];
    const float4 b4 = *(const float4*)&B[(size_t)(k0 + br) * NF + n0 + bc];
    As[ac + 0][ar] = a4.x;
    As[ac + 1][ar] = a4.y;
    As[ac + 2][ar] = a4.z;
    As[ac + 3][ar] = a4.w;
    *(float4*)&Bs[br][bc] = b4;
    __syncthreads();
#pragma unroll
    for (int kk = 0; kk < 16; ++kk) {
      const float4 av = *(const float4*)&As[kk][i0];
      const float4 bv = *(const float4*)&Bs[kk][j0];
      const float a_[4] = {av.x, av.y, av.z, av.w};
      const float b_[4] = {bv.x, bv.y, bv.z, bv.w};
#pragma unroll
      for (int i = 0; i < 4; ++i)
#pragma unroll
        for (int j = 0; j < 4; ++j)
          acc[i][j] = fmaf(a_[i], b_[j], acc[i][j]);
    }
    __syncthreads();
  }
#pragma unroll
  for (int i = 0; i < 4; ++i) {
    float4 o;
    o.x = acc[i][0] > 0.f ? acc[i][0] + 1.f : expf(acc[i][0]);
    o.y = acc[i][1] > 0.f ? acc[i][1] + 1.f : expf(acc[i][1]);
    o.z = acc[i][2] > 0.f ? acc[i][2] + 1.f : expf(acc[i][2]);
    o.w = acc[i][3] > 0.f ? acc[i][3] + 1.f : expf(acc[i][3]);
    *(float4*)&C[(size_t)(m0 + i0 + i) * NF + n0 + j0] = o;
  }
}

// ---------------- per-chunk K^T V sums (and K column sums) ----------------
__global__ __launch_bounds__(256) void chunk_sums(
    const float* __restrict__ qkv, const float* __restrict__ k_proj,
    float* __restrict__ kvsum, float* __restrict__ ksum)
{
  __shared__ float Kp[CHUNK][NF];
  __shared__ float Vs[CHUNK][HD];
  const int c = blockIdx.x, h = blockIdx.y;
  const int t = threadIdx.x;
  const float* kp_base = k_proj + ((size_t)h * NTOK + c * CHUNK) * NF;
  const float* v_base  = qkv + (size_t)(c * CHUNK) * QKV_LD + 2 * DMODEL + h * HD;
  for (int idx = t; idx < CHUNK * 32; idx += 256) {
    const int r = idx >> 5, c4 = (idx & 31) * 4;
    *(float4*)&Kp[r][c4] = *(const float4*)&kp_base[r * NF + c4];
  }
  for (int idx = t; idx < CHUNK * 16; idx += 256) {
    const int r = idx >> 4, c4 = (idx & 15) * 4;
    *(float4*)&Vs[r][c4] = *(const float4*)&v_base[(size_t)r * QKV_LD + c4];
  }
  __syncthreads();
  const int f0 = (t & 31) * 4;
  const int d0 = (t >> 5) * 8;
  float acc[4][8] = {};
  for (int j = 0; j < CHUNK; ++j) {
    const float4 kv = *(const float4*)&Kp[j][f0];
    const float k_[4] = {kv.x, kv.y, kv.z, kv.w};
    const float4 v0 = *(const float4*)&Vs[j][d0];
    const float4 v1 = *(const float4*)&Vs[j][d0 + 4];
    const float v_[8] = {v0.x, v0.y, v0.z, v0.w, v1.x, v1.y, v1.z, v1.w};
#pragma unroll
    for (int i = 0; i < 4; ++i)
#pragma unroll
      for (int jj = 0; jj < 8; ++jj)
        acc[i][jj] = fmaf(k_[i], v_[jj], acc[i][jj]);
  }
  float* outp = kvsum + ((size_t)h * NCHUNK + c) * NF * HD;
#pragma unroll
  for (int i = 0; i < 4; ++i) {
    float4 r0, r1;
    r0.x = acc[i][0]; r0.y = acc[i][1]; r0.z = acc[i][2]; r0.w = acc[i][3];
    r1.x = acc[i][4]; r1.y = acc[i][5]; r1.z = acc[i][6]; r1.w = acc[i][7];
    *(float4*)&outp[(f0 + i) * HD + d0]     = r0;
    *(float4*)&outp[(f0 + i) * HD + d0 + 4] = r1;
  }
  if (t < 32) {
#pragma unroll
    for (int q = 0; q < 4; ++q) {
      const int f = t * 4 + q;
      float s = 0.f;
      for (int j = 0; j < CHUNK; ++j) s += Kp[j][f];
      ksum[((size_t)h * NCHUNK + c) * NF + f] = s;
    }
  }
}

// ---------------- in-place exclusive prefix over chunks ----------------
__global__ __launch_bounds__(256) void chunk_scan(
    float* __restrict__ kvsum, float* __restrict__ ksum)
{
  const int h = blockIdx.y;
  const int t = threadIdx.x;
  if (blockIdx.x < NCHUNK) {
    const int e = blockIdx.x * 256 + t;
    const size_t base = (size_t)h * NCHUNK * NF * HD + e;
    float run = 0.f;
    for (int c = 0; c < NCHUNK; ++c) {
      const size_t idx = base + (size_t)c * NF * HD;
      const float v = kvsum[idx];
      kvsum[idx] = run;
      run += v;
    }
  } else if (t < NF) {
    const size_t base = (size_t)h * NCHUNK * NF + t;
    float run = 0.f;
    for (int c = 0; c < NCHUNK; ++c) {
      const size_t idx = base + (size_t)c * NF;
      const float v = ksum[idx];
      ksum[idx] = run;
      run += v;
    }
  }
}

// ---------------- per-chunk attention; emits attn as bf16 ----------------
__global__ __launch_bounds__(256) void chunk_attn(
    const float* __restrict__ qkv, const float* __restrict__ q_proj,
    const float* __restrict__ k_proj, const float* __restrict__ kvpre,
    const float* __restrict__ kpre, unsigned short* __restrict__ attnb)
{
  __shared__ float Qph[CHUNK][68];
  __shared__ float Kph[CHUNK][68];
  __shared__ float Sb[CHUNK][68];
  __shared__ float den[CHUNK];
  const int c = blockIdx.x, h = blockIdx.y;
  const int t = threadIdx.x;
  const int i0 = (t >> 4) * 4;
  const int j0 = (t & 15) * 4;
  const float* qp_base   = q_proj + ((size_t)h * NTOK + c * CHUNK) * NF;
  const float* kp_base   = k_proj + ((size_t)h * NTOK + c * CHUNK) * NF;
  const float* kvp_base  = kvpre + ((size_t)h * NCHUNK + c) * NF * HD;
  const float* kpre_base = kpre + ((size_t)h * NCHUNK + c) * NF;
  float s_[4][4] = {};
  float o_[4][4] = {};
  float pd = 0.f;
#pragma unroll
  for (int p = 0; p < 2; ++p) {
    for (int idx = t; idx < CHUNK * 16; idx += 256) {
      const int r = idx >> 4, c4 = (idx & 15) * 4;
      *(float4*)&Qph[r][c4] = *(const float4*)&qp_base[r * NF + p * 64 + c4];
      *(float4*)&Kph[r][c4] = *(const float4*)&kp_base[r * NF + p * 64 + c4];
      *(float4*)&Sb[r][c4]  = *(const float4*)&kvp_base[(p * 64 + r) * HD + c4];
    }
    __syncthreads();
#pragma unroll 4
    for (int f = 0; f < 64; f += 4) {
      float q_[4][4], k_[4][4];
#pragma unroll
      for (int i = 0; i < 4; ++i) {
        const float4 qa = *(const float4*)&Qph[i0 + i][f];
        q_[i][0] = qa.x; q_[i][1] = qa.y; q_[i][2] = qa.z; q_[i][3] = qa.w;
        const float4 kb = *(const float4*)&Kph[j0 + i][f];
        k_[i][0] = kb.x; k_[i][1] = kb.y; k_[i][2] = kb.z; k_[i][3] = kb.w;
      }
#pragma unroll
      for (int i = 0; i < 4; ++i)
#pragma unroll
        for (int j = 0; j < 4; ++j)
          s_[i][j] += q_[i][0] * k_[j][0] + q_[i][1] * k_[j][1]
                    + q_[i][2] * k_[j][2] + q_[i][3] * k_[j][3];
#pragma unroll
      for (int ff = 0; ff < 4; ++ff) {
        const float4 pv = *(const float4*)&Sb[f + ff][j0];
#pragma unroll
        for (int i = 0; i < 4; ++i) {
          o_[i][0] = fmaf(q_[i][ff], pv.x, o_[i][0]);
          o_[i][1] = fmaf(q_[i][ff], pv.y, o_[i][1]);
          o_[i][2] = fmaf(q_[i][ff], pv.z, o_[i][2]);
          o_[i][3] = fmaf(q_[i][ff], pv.w, o_[i][3]);
        }
      }
    }
    if (t < CHUNK) {
#pragma unroll 8
      for (int f = 0; f < 64; ++f)
        pd = fmaf(Qph[t][f], kpre_base[p * 64 + f], pd);
    }
    __syncthreads();
  }
#pragma unroll
  for (int i = 0; i < 4; ++i)
#pragma unroll
    for (int j = 0; j < 4; ++j)
      Sb[i0 + i][j0 + j] = s_[i][j];
  const float* v_base = qkv + (size_t)(c * CHUNK) * QKV_LD + 2 * DMODEL + h * HD;
  for (int idx = t; idx < CHUNK * 16; idx += 256) {
    const int r = idx >> 4, c4 = (idx & 15) * 4;
    *(float4*)&Kph[r][c4] = *(const float4*)&v_base[(size_t)r * QKV_LD + c4];
  }
  __syncthreads();
  if (t < CHUNK) {
    float rs = 0.f;
    for (int j = 0; j <= t; ++j) rs += Sb[t][j];
    den[t] = pd + rs + EPS_C;
  }
  __syncthreads();
  for (int j = 0; j < CHUNK; ++j) {
    const float4 vv = *(const float4*)&Kph[j][j0];
#pragma unroll
    for (int i = 0; i < 4; ++i) {
      const float sj = (j <= i0 + i) ? Sb[i0 + i][j] : 0.f;
      o_[i][0] = fmaf(sj, vv.x, o_[i][0]);
      o_[i][1] = fmaf(sj, vv.y, o_[i][1]);
      o_[i][2] = fmaf(sj, vv.z, o_[i][2]);
      o_[i][3] = fmaf(sj, vv.w, o_[i][3]);
    }
  }
#pragma unroll
  for (int i = 0; i < 4; ++i) {
    const float dinv = 1.0f / den[i0 + i];
    ushort4 r;
    r.x = f2bf(o_[i][0] * dinv);
    r.y = f2bf(o_[i][1] * dinv);
    r.z = f2bf(o_[i][2] * dinv);
    r.w = f2bf(o_[i][3] * dinv);
    *(ushort4*)&attnb[(size_t)(c * CHUNK + i0 + i) * DMODEL + h * HD + j0] = r;
  }
}

extern "C" void kernel_launch(void* const* d_in, const int* in_sizes, int n_in,
                              void* d_out, int out_size, void* d_ws, size_t ws_size,
                              hipStream_t stream) {
  const float* x     = (const float*)d_in[0];
  const float* proj  = (const float*)d_in[1];
  const float* W_qkv = (const float*)d_in[2];
  const float* W_out = (const float*)d_in[3];
  const float* b_out = (const float*)d_in[4];
  float* out = (float*)d_out;
  float* ws = (float*)d_ws;

  float* qkv    = ws;                                   // 3,145,728 f
  float* q_proj = qkv + (size_t)NTOK * QKV_LD;          // 2,097,152 f
  float* k_proj = q_proj + (size_t)NH * NTOK * NF;      // 2,097,152 f
  float* kvsum  = k_proj + (size_t)NH * NTOK * NF;      // 2,097,152 f
  float* ksum   = kvsum + (size_t)NH * NCHUNK * NF * HD; // 32,768 f
  unsigned short* xbf   = (unsigned short*)(ksum + (size_t)NH * NCHUNK * NF); // 1,048,576 us
  unsigned short* attnb = xbf;  // overlay: xbf dead after GEMM1; attnb written at step 5
  unsigned short* wqkvT = xbf + (size_t)NTOK * DMODEL;      // 786,432 us
  unsigned short* woutT = wqkvT + (size_t)DMODEL * QKV_LD;  // 262,144 us
  // total: 10,518,528 floats (~42.1 MB) — same footprint as round 2

  // 0) conversions
  cvt_bf16<<<dim3(NTOK * DMODEL / 1024), 256, 0, stream>>>(x, xbf, NTOK * DMODEL);
  cvt_T<<<dim3(QKV_LD / 32, DMODEL / 32), 256, 0, stream>>>(W_qkv, wqkvT, DMODEL, QKV_LD);
  cvt_T<<<dim3(DMODEL / 32, DMODEL / 32), 256, 0, stream>>>(W_out, woutT, DMODEL, DMODEL);
  // 1) qkv = x @ W_qkv  (bf16 MFMA, f32 out)
  gemm_mfma<false><<<dim3(QKV_LD / 64, NTOK / 64), 256, 0, stream>>>(
      xbf, wqkvT, nullptr, qkv, DMODEL, QKV_LD);
  // 2) q_proj/k_proj = elu(head-GEMM)+1
  proj_gemm<<<dim3(NTOK / 64, 4, NH), 256, 0, stream>>>(qkv, proj, q_proj, k_proj);
  // 3) per-chunk K^T V and K sums
  chunk_sums<<<dim3(NCHUNK, NH), 256, 0, stream>>>(qkv, k_proj, kvsum, ksum);
  // 4) exclusive prefix over chunks
  chunk_scan<<<dim3(NCHUNK + 1, NH), 256, 0, stream>>>(kvsum, ksum);
  // 5) per-chunk attention -> attn in bf16
  chunk_attn<<<dim3(NCHUNK, NH), 256, 0, stream>>>(qkv, q_proj, k_proj, kvsum, ksum, attnb);
  // 6) out = attn @ W_out + b_out  (bf16 MFMA, f32 out)
  gemm_mfma<true><<<dim3(DMODEL / 64, NTOK / 64), 256, 0, stream>>>(
      attnb, woutT, b_out, out, DMODEL, DMODEL);
}

// Round 4
// 77.762 us; speedup vs baseline: 1.7724x; 1.3493x over previous
//
#include <hip/hip_runtime.h>
#include <math.h>

#define NTOK 2048
#define DMODEL 512
#define NH 8
#define HD 64
#define NF 128
#define QKV_LD 1536
#define CHUNK 64
#define NCHUNK 32
#define EPS_C 1e-8f

typedef __bf16 bf16x8 __attribute__((ext_vector_type(8)));
typedef float f32x4 __attribute__((ext_vector_type(4)));

__device__ inline unsigned short f2bf(float f) {
  union { float f; unsigned u; } v; v.f = f;
  unsigned r = v.u + 0x7FFF + ((v.u >> 16) & 1);   // RNE
  return (unsigned short)(r >> 16);
}

// ============ pack_all: fp32 -> bf16 in MFMA-fragment order ============
// Packed layout for a row-major MxK operand: unit8 index
//   (( (m>>4)*(K>>5) + (k>>5) )*64 + (m&15) + ((k>>3)&3)*16 )  * 8 + (k&7)
// job 0: x (2048x512, same orientation)      -> xpk      (131072 units)
// job 1: W_qkv^T (N=1536 rows, K=512)        -> wqkvpk   ( 98304 units)
// job 2: W_out^T (N=512, K=512)              -> woutpk   ( 32768 units)
// job 3: proj^T per head (N=128, K=64) x 8   -> projpk   (  8192 units)
__global__ __launch_bounds__(256) void pack_all(
    const float* __restrict__ x, const float* __restrict__ W_qkv,
    const float* __restrict__ W_out, const float* __restrict__ proj,
    unsigned short* __restrict__ xpk, unsigned short* __restrict__ wqkvpk,
    unsigned short* __restrict__ woutpk, unsigned short* __restrict__ projpk)
{
  const int tid = blockIdx.x * 256 + threadIdx.x;
  const int job = blockIdx.y;
  unsigned short o[8];
  if (job == 0) {
    if (tid >= 131072) return;
    const int lane = tid & 63, blk = tid >> 6;
    const int bk = blk & 15, bm = blk >> 4;
    const int m = bm * 16 + (lane & 15), k = bk * 32 + (lane >> 4) * 8;
    const float4 v0 = *(const float4*)&x[(size_t)m * 512 + k];
    const float4 v1 = *(const float4*)&x[(size_t)m * 512 + k + 4];
    o[0] = f2bf(v0.x); o[1] = f2bf(v0.y); o[2] = f2bf(v0.z); o[3] = f2bf(v0.w);
    o[4] = f2bf(v1.x); o[5] = f2bf(v1.y); o[6] = f2bf(v1.z); o[7] = f2bf(v1.w);
    *(ushort4*)&xpk[(size_t)tid * 8]     = *(ushort4*)&o[0];
    *(ushort4*)&xpk[(size_t)tid * 8 + 4] = *(ushort4*)&o[4];
  } else if (job == 1) {
    if (tid >= 98304) return;
    const int lane = tid & 63, blk = tid >> 6;
    const int bk = blk & 15, bn = blk >> 4;
    const int n = bn * 16 + (lane & 15), k = bk * 32 + (lane >> 4) * 8;
#pragma unroll
    for (int e = 0; e < 8; ++e) o[e] = f2bf(W_qkv[(size_t)(k + e) * QKV_LD + n]);
    *(ushort4*)&wqkvpk[(size_t)tid * 8]     = *(ushort4*)&o[0];
    *(ushort4*)&wqkvpk[(size_t)tid * 8 + 4] = *(ushort4*)&o[4];
  } else if (job == 2) {
    if (tid >= 32768) return;
    const int lane = tid & 63, blk = tid >> 6;
    const int bk = blk & 15, bn = blk >> 4;
    const int n = bn * 16 + (lane & 15), k = bk * 32 + (lane >> 4) * 8;
#pragma unroll
    for (int e = 0; e < 8; ++e) o[e] = f2bf(W_out[(size_t)(k + e) * DMODEL + n]);
    *(ushort4*)&woutpk[(size_t)tid * 8]     = *(ushort4*)&o[0];
    *(ushort4*)&woutpk[(size_t)tid * 8 + 4] = *(ushort4*)&o[4];
  } else {
    if (tid >= 8192) return;
    const int lane = tid & 63, blk = (tid >> 6) & 15, h = tid >> 10;
    const int bk = blk & 1, bn = blk >> 1;
    const int n = bn * 16 + (lane & 15), k = bk * 32 + (lane >> 4) * 8;
#pragma unroll
    for (int e = 0; e < 8; ++e) o[e] = f2bf(proj[(size_t)h * HD * NF + (size_t)(k + e) * NF + n]);
    *(ushort4*)&projpk[(size_t)tid * 8]     = *(ushort4*)&o[0];
    *(ushort4*)&projpk[(size_t)tid * 8 + 4] = *(ushort4*)&o[4];
  }
}

// ============ packed-fragment bf16 MFMA GEMM ============
// EMIT 0: C = A@Bt^T (+bias) -> Cf row-major (ldc)
// EMIT 1 (qkv mode): col<1024 -> Cb bf16 row-major stride 1024 (Q,K);
//                    col>=1024 -> Cf f32 compact stride 512 (V)
template<bool BIAS, int EMIT>
__global__ __launch_bounds__(256) void gemm_pk(
    const unsigned short* __restrict__ Apk, const unsigned short* __restrict__ Bpk,
    const float* __restrict__ bias, float* __restrict__ Cf,
    unsigned short* __restrict__ Cb, int K, int ldc)
{
  const int lane = threadIdx.x & 63, w = threadIdx.x >> 6;
  const int wr = w >> 1, wc = w & 1;
  const int m0 = blockIdx.y * 64 + wr * 32;
  const int n0 = blockIdx.x * 64 + wc * 32;
  const int ks = K >> 5;
  const unsigned short* a0 = Apk + ((size_t)(m0 >> 4) * ks * 64 + lane) * 8;
  const unsigned short* a1 = a0 + (size_t)ks * 512;
  const unsigned short* b0 = Bpk + ((size_t)(n0 >> 4) * ks * 64 + lane) * 8;
  const unsigned short* b1 = b0 + (size_t)ks * 512;
  f32x4 acc00 = {0.f, 0.f, 0.f, 0.f}, acc01 = acc00, acc10 = acc00, acc11 = acc00;
#pragma unroll 4
  for (int s = 0; s < ks; ++s) {
    const bf16x8 af0 = *(const bf16x8*)(a0 + (size_t)s * 512);
    const bf16x8 af1 = *(const bf16x8*)(a1 + (size_t)s * 512);
    const bf16x8 bv0 = *(const bf16x8*)(b0 + (size_t)s * 512);
    const bf16x8 bv1 = *(const bf16x8*)(b1 + (size_t)s * 512);
    acc00 = __builtin_amdgcn_mfma_f32_16x16x32_bf16(af0, bv0, acc00, 0, 0, 0);
    acc01 = __builtin_amdgcn_mfma_f32_16x16x32_bf16(af0, bv1, acc01, 0, 0, 0);
    acc10 = __builtin_amdgcn_mfma_f32_16x16x32_bf16(af1, bv0, acc10, 0, 0, 0);
    acc11 = __builtin_amdgcn_mfma_f32_16x16x32_bf16(af1, bv1, acc11, 0, 0, 0);
  }
  const int r16 = lane & 15, kg = lane >> 4;
#pragma unroll
  for (int mb = 0; mb < 2; ++mb) {
#pragma unroll
    for (int nb = 0; nb < 2; ++nb) {
      const f32x4 a = mb == 0 ? (nb == 0 ? acc00 : acc01) : (nb == 0 ? acc10 : acc11);
      const int col = n0 + nb * 16 + r16;
      if (EMIT == 1) {
        if (col < 1024) {
#pragma unroll
          for (int r = 0; r < 4; ++r)
            Cb[(size_t)(m0 + mb * 16 + kg * 4 + r) * 1024 + col] = f2bf(a[r]);
        } else {
#pragma unroll
          for (int r = 0; r < 4; ++r)
            Cf[(size_t)(m0 + mb * 16 + kg * 4 + r) * 512 + col - 1024] = a[r];
        }
      } else {
        const float bv = BIAS ? bias[col] : 0.f;
#pragma unroll
        for (int r = 0; r < 4; ++r)
          Cf[(size_t)(m0 + mb * 16 + kg * 4 + r) * ldc + col] = a[r] + bv;
      }
    }
  }
}

// ============ proj via MFMA + fused elu+1 ============
// grid (NTOK/64, 2 src, NH). Block: 64 tokens x 128 features, 4 waves.
__global__ __launch_bounds__(256) void proj_mfma(
    const unsigned short* __restrict__ qkvb, const unsigned short* __restrict__ projpk,
    float* __restrict__ q_proj, float* __restrict__ k_proj)
{
  const int lane = threadIdx.x & 63, w = threadIdx.x >> 6;
  const int wr = w & 1, wc = w >> 1;          // row half, col half
  const int m0 = blockIdx.x * 64 + wr * 32;
  const int src = blockIdx.y, h = blockIdx.z;
  const int r16 = lane & 15, kg = lane >> 4;
  const unsigned short* abase = qkvb + (size_t)(m0 + r16) * 1024 + src * 512 + h * HD + kg * 8;
  const unsigned short* bbase = projpk + (size_t)h * 8192 + (size_t)lane * 8;
  f32x4 acc[2][4] = {};
#pragma unroll
  for (int s = 0; s < 2; ++s) {
    const bf16x8 af0 = *(const bf16x8*)(abase + s * 32);
    const bf16x8 af1 = *(const bf16x8*)(abase + (size_t)16 * 1024 + s * 32);
#pragma unroll
    for (int nb = 0; nb < 4; ++nb) {
      const bf16x8 bv = *(const bf16x8*)(bbase + (size_t)((wc * 4 + nb) * 2 + s) * 512);
      acc[0][nb] = __builtin_amdgcn_mfma_f32_16x16x32_bf16(af0, bv, acc[0][nb], 0, 0, 0);
      acc[1][nb] = __builtin_amdgcn_mfma_f32_16x16x32_bf16(af1, bv, acc[1][nb], 0, 0, 0);
    }
  }
  float* C = (src ? k_proj : q_proj) + (size_t)h * NTOK * NF;
#pragma unroll
  for (int mb = 0; mb < 2; ++mb)
#pragma unroll
    for (int nb = 0; nb < 4; ++nb)
#pragma unroll
      for (int r = 0; r < 4; ++r) {
        const int m = m0 + mb * 16 + kg * 4 + r;
        const int col = wc * 64 + nb * 16 + r16;
        const float v = acc[mb][nb][r];
        C[(size_t)m * NF + col] = v > 0.f ? v + 1.f : expf(v);
      }
}

// ============ per-chunk K^T V sums (and K column sums), fp32 ============
__global__ __launch_bounds__(256) void chunk_sums(
    const float* __restrict__ vbuf, const float* __restrict__ k_proj,
    float* __restrict__ kvsum, float* __restrict__ ksum)
{
  __shared__ float Kp[CHUNK][NF];
  __shared__ float Vs[CHUNK][HD];
  const int c = blockIdx.x, h = blockIdx.y;
  const int t = threadIdx.x;
  const float* kp_base = k_proj + ((size_t)h * NTOK + c * CHUNK) * NF;
  const float* v_base  = vbuf + (size_t)(c * CHUNK) * 512 + h * HD;
  for (int idx = t; idx < CHUNK * 32; idx += 256) {
    const int r = idx >> 5, c4 = (idx & 31) * 4;
    *(float4*)&Kp[r][c4] = *(const float4*)&kp_base[r * NF + c4];
  }
  for (int idx = t; idx < CHUNK * 16; idx += 256) {
    const int r = idx >> 4, c4 = (idx & 15) * 4;
    *(float4*)&Vs[r][c4] = *(const float4*)&v_base[(size_t)r * 512 + c4];
  }
  __syncthreads();
  const int f0 = (t & 31) * 4;
  const int d0 = (t >> 5) * 8;
  float acc[4][8] = {};
  for (int j = 0; j < CHUNK; ++j) {
    const float4 kv = *(const float4*)&Kp[j][f0];
    const float k_[4] = {kv.x, kv.y, kv.z, kv.w};
    const float4 v0 = *(const float4*)&Vs[j][d0];
    const float4 v1 = *(const float4*)&Vs[j][d0 + 4];
    const float v_[8] = {v0.x, v0.y, v0.z, v0.w, v1.x, v1.y, v1.z, v1.w};
#pragma unroll
    for (int i = 0; i < 4; ++i)
#pragma unroll
      for (int jj = 0; jj < 8; ++jj)
        acc[i][jj] = fmaf(k_[i], v_[jj], acc[i][jj]);
  }
  float* outp = kvsum + ((size_t)h * NCHUNK + c) * NF * HD;
#pragma unroll
  for (int i = 0; i < 4; ++i) {
    float4 r0, r1;
    r0.x = acc[i][0]; r0.y = acc[i][1]; r0.z = acc[i][2]; r0.w = acc[i][3];
    r1.x = acc[i][4]; r1.y = acc[i][5]; r1.z = acc[i][6]; r1.w = acc[i][7];
    *(float4*)&outp[(f0 + i) * HD + d0]     = r0;
    *(float4*)&outp[(f0 + i) * HD + d0 + 4] = r1;
  }
  if (t < 32) {
#pragma unroll
    for (int q = 0; q < 4; ++q) {
      const int f = t * 4 + q;
      float s = 0.f;
      for (int j = 0; j < CHUNK; ++j) s += Kp[j][f];
      ksum[((size_t)h * NCHUNK + c) * NF + f] = s;
    }
  }
}

// ============ in-place exclusive prefix over chunks ============
__global__ __launch_bounds__(256) void chunk_scan(
    float* __restrict__ kvsum, float* __restrict__ ksum)
{
  const int h = blockIdx.y;
  const int t = threadIdx.x;
  if (blockIdx.x < NCHUNK) {
    const int e = blockIdx.x * 256 + t;
    const size_t base = (size_t)h * NCHUNK * NF * HD + e;
    float run = 0.f;
    for (int c = 0; c < NCHUNK; ++c) {
      const size_t idx = base + (size_t)c * NF * HD;
      const float v = kvsum[idx];
      kvsum[idx] = run;
      run += v;
    }
  } else if (t < NF) {
    const size_t base = (size_t)h * NCHUNK * NF + t;
    float run = 0.f;
    for (int c = 0; c < NCHUNK; ++c) {
      const size_t idx = base + (size_t)c * NF;
      const float v = ksum[idx];
      ksum[idx] = run;
      run += v;
    }
  }
}

// ============ per-chunk attention; emits attn bf16 in PACKED layout ======
__global__ __launch_bounds__(256) void chunk_attn(
    const float* __restrict__ vbuf, const float* __restrict__ q_proj,
    const float* __restrict__ k_proj, const float* __restrict__ kvpre,
    const float* __restrict__ kpre, unsigned short* __restrict__ attnpk)
{
  __shared__ float Qph[CHUNK][68];
  __shared__ float Kph[CHUNK][68];
  __shared__ float Sb[CHUNK][68];
  __shared__ float den[CHUNK];
  const int c = blockIdx.x, h = blockIdx.y;
  const int t = threadIdx.x;
  const int i0 = (t >> 4) * 4;
  const int j0 = (t & 15) * 4;
  const float* qp_base   = q_proj + ((size_t)h * NTOK + c * CHUNK) * NF;
  const float* kp_base   = k_proj + ((size_t)h * NTOK + c * CHUNK) * NF;
  const float* kvp_base  = kvpre + ((size_t)h * NCHUNK + c) * NF * HD;
  const float* kpre_base = kpre + ((size_t)h * NCHUNK + c) * NF;
  float s_[4][4] = {};
  float o_[4][4] = {};
  float pd = 0.f;
#pragma unroll
  for (int p = 0; p < 2; ++p) {
    for (int idx = t; idx < CHUNK * 16; idx += 256) {
      const int r = idx >> 4, c4 = (idx & 15) * 4;
      *(float4*)&Qph[r][c4] = *(const float4*)&qp_base[r * NF + p * 64 + c4];
      *(float4*)&Kph[r][c4] = *(const float4*)&kp_base[r * NF + p * 64 + c4];
      *(float4*)&Sb[r][c4]  = *(const float4*)&kvp_base[(p * 64 + r) * HD + c4];
    }
    __syncthreads();
#pragma unroll 4
    for (int f = 0; f < 64; f += 4) {
      float q_[4][4], k_[4][4];
#pragma unroll
      for (int i = 0; i < 4; ++i) {
        const float4 qa = *(const float4*)&Qph[i0 + i][f];
        q_[i][0] = qa.x; q_[i][1] = qa.y; q_[i][2] = qa.z; q_[i][3] = qa.w;
        const float4 kb = *(const float4*)&Kph[j0 + i][f];
        k_[i][0] = kb.x; k_[i][1] = kb.y; k_[i][2] = kb.z; k_[i][3] = kb.w;
      }
#pragma unroll
      for (int i = 0; i < 4; ++i)
#pragma unroll
        for (int j = 0; j < 4; ++j)
          s_[i][j] += q_[i][0] * k_[j][0] + q_[i][1] * k_[j][1]
                    + q_[i][2] * k_[j][2] + q_[i][3] * k_[j][3];
#pragma unroll
      for (int ff = 0; ff < 4; ++ff) {
        const float4 pv = *(const float4*)&Sb[f + ff][j0];
#pragma unroll
        for (int i = 0; i < 4; ++i) {
          o_[i][0] = fmaf(q_[i][ff], pv.x, o_[i][0]);
          o_[i][1] = fmaf(q_[i][ff], pv.y, o_[i][1]);
          o_[i][2] = fmaf(q_[i][ff], pv.z, o_[i][2]);
          o_[i][3] = fmaf(q_[i][ff], pv.w, o_[i][3]);
        }
      }
    }
    if (t < CHUNK) {
#pragma unroll 8
      for (int f = 0; f < 64; ++f)
        pd = fmaf(Qph[t][f], kpre_base[p * 64 + f], pd);
    }
    __syncthreads();
  }
#pragma unroll
  for (int i = 0; i < 4; ++i)
#pragma unroll
    for (int j = 0; j < 4; ++j)
      Sb[i0 + i][j0 + j] = s_[i][j];
  const float* v_base = vbuf + (size_t)(c * CHUNK) * 512 + h * HD;
  for (int idx = t; idx < CHUNK * 16; idx += 256) {
    const int r = idx >> 4, c4 = (idx & 15) * 4;
    *(float4*)&Kph[r][c4] = *(const float4*)&v_base[(size_t)r * 512 + c4];
  }
  __syncthreads();
  if (t < CHUNK) {
    float rs = 0.f;
    for (int j = 0; j <= t; ++j) rs += Sb[t][j];
    den[t] = pd + rs + EPS_C;
  }
  __syncthreads();
  for (int j = 0; j < CHUNK; ++j) {
    const float4 vv = *(const float4*)&Kph[j][j0];
#pragma unroll
    for (int i = 0; i < 4; ++i) {
      const float sj = (j <= i0 + i) ? Sb[i0 + i][j] : 0.f;
      o_[i][0] = fmaf(sj, vv.x, o_[i][0]);
      o_[i][1] = fmaf(sj, vv.y, o_[i][1]);
      o_[i][2] = fmaf(sj, vv.z, o_[i][2]);
      o_[i][3] = fmaf(sj, vv.w, o_[i][3]);
    }
  }
  // write attn in packed-fragment layout (K dim = 512, ks = 16)
#pragma unroll
  for (int i = 0; i < 4; ++i) {
    const float dinv = 1.0f / den[i0 + i];
    const int m = c * CHUNK + i0 + i;
    const int col = h * HD + j0;            // multiple of 4; col&7 in {0,4}
    const size_t a8 = ((size_t)(m >> 4) * 16 + (col >> 5)) * 64 + (m & 15) + ((col >> 3) & 3) * 16;
    ushort4 r;
    r.x = f2bf(o_[i][0] * dinv);
    r.y = f2bf(o_[i][1] * dinv);
    r.z = f2bf(o_[i][2] * dinv);
    r.w = f2bf(o_[i][3] * dinv);
    *(ushort4*)&attnpk[a8 * 8 + (col & 4)] = r;
  }
}

extern "C" void kernel_launch(void* const* d_in, const int* in_sizes, int n_in,
                              void* d_out, int out_size, void* d_ws, size_t ws_size,
                              hipStream_t stream) {
  const float* x     = (const float*)d_in[0];
  const float* proj  = (const float*)d_in[1];
  const float* W_qkv = (const float*)d_in[2];
  const float* W_out = (const float*)d_in[3];
  const float* b_out = (const float*)d_in[4];
  float* out = (float*)d_out;
  float* ws = (float*)d_ws;

  float* qkv_v  = ws;                                        // 1,048,576 f (V compact)
  float* q_proj = qkv_v + (size_t)NTOK * 512;                // 2,097,152 f
  float* k_proj = q_proj + (size_t)NH * NTOK * NF;           // 2,097,152 f
  float* kvsum  = k_proj + (size_t)NH * NTOK * NF;           // 2,097,152 f
  float* ksum   = kvsum + (size_t)NH * NCHUNK * NF * HD;     //    32,768 f
  unsigned short* xpk    = (unsigned short*)(ksum + (size_t)NH * NCHUNK * NF);
  unsigned short* wqkvpk = xpk + (size_t)131072 * 8;         //   786,432 us
  unsigned short* woutpk = wqkvpk + (size_t)98304 * 8;       //   262,144 us
  unsigned short* projpk = woutpk + (size_t)32768 * 8;       //    65,536 us
  unsigned short* qkvb   = projpk + (size_t)8192 * 8;        // 2,097,152 us (Q,K bf16)
  unsigned short* attnpk = qkvb + (size_t)NTOK * 1024;       // 1,048,576 us
  // total ~40 MB

  // 0) pack all operands to bf16 fragment layout (one kernel, 4 jobs)
  pack_all<<<dim3(512, 4), 256, 0, stream>>>(x, W_qkv, W_out, proj,
                                             xpk, wqkvpk, woutpk, projpk);
  // 1) qkv: Q,K -> bf16 row-major; V -> f32 compact
  gemm_pk<false, 1><<<dim3(QKV_LD / 64, NTOK / 64), 256, 0, stream>>>(
      xpk, wqkvpk, nullptr, qkv_v, qkvb, DMODEL, 0);
  // 2) q_proj/k_proj = elu(head-GEMM)+1 via MFMA
  proj_mfma<<<dim3(NTOK / 64, 2, NH), 256, 0, stream>>>(qkvb, projpk, q_proj, k_proj);
  // 3) per-chunk K^T V and K sums
  chunk_sums<<<dim3(NCHUNK, NH), 256, 0, stream>>>(qkv_v, k_proj, kvsum, ksum);
  // 4) exclusive prefix over chunks
  chunk_scan<<<dim3(NCHUNK + 1, NH), 256, 0, stream>>>(kvsum, ksum);
  // 5) per-chunk attention -> attn bf16 packed
  chunk_attn<<<dim3(NCHUNK, NH), 256, 0, stream>>>(qkv_v, q_proj, k_proj, kvsum, ksum, attnpk);
  // 6) out = attn @ W_out + b_out
  gemm_pk<true, 0><<<dim3(DMODEL / 64, NTOK / 64), 256, 0, stream>>>(
      attnpk, woutpk, b_out, out, nullptr, DMODEL, DMODEL);
}

// Round 5
// 55.812 us; speedup vs baseline: 2.4695x; 1.3933x over previous
//
#include <hip/hip_runtime.h>
#include <math.h>

#define NTOK 2048
#define DMODEL 512
#define NH 8
#define HD 64
#define NF 128
#define QKV_LD 1536
#define CHUNK 64
#define NCHUNK 32
#define EPS_C 1e-8f

typedef __bf16 bf16x8 __attribute__((ext_vector_type(8)));
typedef float f32x4 __attribute__((ext_vector_type(4)));

__device__ inline unsigned short f2bf(float f) {
  union { float f; unsigned u; } v; v.f = f;
  unsigned r = v.u + 0x7FFF + ((v.u >> 16) & 1);   // RNE
  return (unsigned short)(r >> 16);
}

// Packed fragment layout PK(M,K) for MFMA operand (A: [m][k]; B: [n][k]):
//   unit(m,k)  = ((m>>4)*(K>>5) + (k>>5))*64 + (m&15) + ((k>>3)&3)*16
//   ushort idx = unit*8 + (k&7)
// Unit counts: xpk PK(2048,512)=131072; wqkvpk PK(1536,512)=98304;
//   woutpk PK(512,512)=32768; projpk 8x PK(128,64)=8192;
//   qkv_pk 16x PK(2048,64)=262144; q_pk/k_pk 8x PK(2048,128)=262144 each;
//   vT_pk 256x PK(80,64)=163840; kvpre_pk 256x PK(80,128)=327680;
//   attn_pk PK(2048,512)=131072.

// ============ pack_all ============
// jobs 0-3: convert inputs to packed bf16. job 4: fill vT_pk n-tile 4
// (cols 64..79 of V'': col 64 = ones, rest zeros).
__global__ __launch_bounds__(256) void pack_all(
    const float* __restrict__ x, const float* __restrict__ W_qkv,
    const float* __restrict__ W_out, const float* __restrict__ proj,
    unsigned short* __restrict__ xpk, unsigned short* __restrict__ wqkvpk,
    unsigned short* __restrict__ woutpk, unsigned short* __restrict__ projpk,
    unsigned short* __restrict__ vT_pk)
{
  const int tid = blockIdx.x * 256 + threadIdx.x;
  const int job = blockIdx.y;
  unsigned short o[8];
  if (job == 0) {
    if (tid >= 131072) return;
    const int lane = tid & 63, blk = tid >> 6;
    const int bk = blk & 15, bm = blk >> 4;
    const int m = bm * 16 + (lane & 15), k = bk * 32 + (lane >> 4) * 8;
    const float4 v0 = *(const float4*)&x[(size_t)m * 512 + k];
    const float4 v1 = *(const float4*)&x[(size_t)m * 512 + k + 4];
    o[0] = f2bf(v0.x); o[1] = f2bf(v0.y); o[2] = f2bf(v0.z); o[3] = f2bf(v0.w);
    o[4] = f2bf(v1.x); o[5] = f2bf(v1.y); o[6] = f2bf(v1.z); o[7] = f2bf(v1.w);
    *(ushort4*)&xpk[(size_t)tid * 8]     = *(ushort4*)&o[0];
    *(ushort4*)&xpk[(size_t)tid * 8 + 4] = *(ushort4*)&o[4];
  } else if (job == 1) {
    if (tid >= 98304) return;
    const int lane = tid & 63, blk = tid >> 6;
    const int bk = blk & 15, bn = blk >> 4;
    const int n = bn * 16 + (lane & 15), k = bk * 32 + (lane >> 4) * 8;
#pragma unroll
    for (int e = 0; e < 8; ++e) o[e] = f2bf(W_qkv[(size_t)(k + e) * QKV_LD + n]);
    *(ushort4*)&wqkvpk[(size_t)tid * 8]     = *(ushort4*)&o[0];
    *(ushort4*)&wqkvpk[(size_t)tid * 8 + 4] = *(ushort4*)&o[4];
  } else if (job == 2) {
    if (tid >= 32768) return;
    const int lane = tid & 63, blk = tid >> 6;
    const int bk = blk & 15, bn = blk >> 4;
    const int n = bn * 16 + (lane & 15), k = bk * 32 + (lane >> 4) * 8;
#pragma unroll
    for (int e = 0; e < 8; ++e) o[e] = f2bf(W_out[(size_t)(k + e) * DMODEL + n]);
    *(ushort4*)&woutpk[(size_t)tid * 8]     = *(ushort4*)&o[0];
    *(ushort4*)&woutpk[(size_t)tid * 8 + 4] = *(ushort4*)&o[4];
  } else if (job == 3) {
    if (tid >= 8192) return;
    const int lane = tid & 63, blk = (tid >> 6) & 15, h = tid >> 10;
    const int bk = blk & 1, bn = blk >> 1;
    const int n = bn * 16 + (lane & 15), k = bk * 32 + (lane >> 4) * 8;
#pragma unroll
    for (int e = 0; e < 8; ++e) o[e] = f2bf(proj[(size_t)h * HD * NF + (size_t)(k + e) * NF + n]);
    *(ushort4*)&projpk[(size_t)tid * 8]     = *(ushort4*)&o[0];
    *(ushort4*)&projpk[(size_t)tid * 8 + 4] = *(ushort4*)&o[4];
  } else {
    if (tid >= 32768) return;                       // 256 (h,c) x 2 kt x 64 lanes
    const int hc = tid >> 7, kt = (tid >> 6) & 1, lane = tid & 63;
    const unsigned short val = ((lane & 15) == 0) ? (unsigned short)0x3F80 : (unsigned short)0;
    const size_t u = (size_t)hc * 640 + (4 * 2 + kt) * 64 + lane;
#pragma unroll
    for (int e = 0; e < 8; ++e) o[e] = val;
    *(ushort4*)&vT_pk[u * 8]     = *(ushort4*)&o[0];
    *(ushort4*)&vT_pk[u * 8 + 4] = *(ushort4*)&o[4];
  }
}

// ============ packed bf16 MFMA GEMM ============
// EMIT 0: Cf = A@B^T (+bias), f32 row-major.
// EMIT 1 (qkv): cols<1024 (Q,K) -> qkv_pk PK(2048,64) per (src,h);
//               cols>=1024 (V)  -> vT_pk PK(80,64) per (h,c) (transposed).
template<bool BIAS, int EMIT>
__global__ __launch_bounds__(256) void gemm_pk(
    const unsigned short* __restrict__ Apk, const unsigned short* __restrict__ Bpk,
    const float* __restrict__ bias, float* __restrict__ Cf,
    unsigned short* __restrict__ qkv_pk, unsigned short* __restrict__ vT_pk,
    int K, int ldc)
{
  const int lane = threadIdx.x & 63, w = threadIdx.x >> 6;
  const int wr = w >> 1, wc = w & 1;
  const int m0 = blockIdx.y * 64 + wr * 32;
  const int n0 = blockIdx.x * 64 + wc * 32;
  const int ks = K >> 5;
  const unsigned short* a0 = Apk + ((size_t)(m0 >> 4) * ks * 64 + lane) * 8;
  const unsigned short* a1 = a0 + (size_t)ks * 512;
  const unsigned short* b0 = Bpk + ((size_t)(n0 >> 4) * ks * 64 + lane) * 8;
  const unsigned short* b1 = b0 + (size_t)ks * 512;
  f32x4 acc00 = {0.f, 0.f, 0.f, 0.f}, acc01 = acc00, acc10 = acc00, acc11 = acc00;
#pragma unroll 4
  for (int s = 0; s < ks; ++s) {
    const bf16x8 af0 = *(const bf16x8*)(a0 + (size_t)s * 512);
    const bf16x8 af1 = *(const bf16x8*)(a1 + (size_t)s * 512);
    const bf16x8 bv0 = *(const bf16x8*)(b0 + (size_t)s * 512);
    const bf16x8 bv1 = *(const bf16x8*)(b1 + (size_t)s * 512);
    acc00 = __builtin_amdgcn_mfma_f32_16x16x32_bf16(af0, bv0, acc00, 0, 0, 0);
    acc01 = __builtin_amdgcn_mfma_f32_16x16x32_bf16(af0, bv1, acc01, 0, 0, 0);
    acc10 = __builtin_amdgcn_mfma_f32_16x16x32_bf16(af1, bv0, acc10, 0, 0, 0);
    acc11 = __builtin_amdgcn_mfma_f32_16x16x32_bf16(af1, bv1, acc11, 0, 0, 0);
  }
  const int r16 = lane & 15, kg = lane >> 4;
#pragma unroll
  for (int mb = 0; mb < 2; ++mb) {
#pragma unroll
    for (int nb = 0; nb < 2; ++nb) {
      const f32x4 a = mb == 0 ? (nb == 0 ? acc00 : acc01) : (nb == 0 ? acc10 : acc11);
      const int col = n0 + nb * 16 + r16;
      if (EMIT == 1) {
        if (col < 1024) {
          // Q,K -> qkv_pk[(src*8+h)] PK(2048,64)
          const int src = col >> 9, h = (col >> 6) & 7;
          const size_t base = (size_t)(src * 8 + h) * 16384 +
              ((size_t)((m0 >> 4) + mb) * 2 + wc) * 64 +
              ((nb * 2 + (r16 >> 3)) & 3) * 16;
          const int elem = r16 & 7;
#pragma unroll
          for (int r = 0; r < 4; ++r)
            qkv_pk[(base + kg * 4 + r) * 8 + elem] = f2bf(a[r]);
        } else {
          // V -> vT_pk[(h*32+c)] PK(80,64): transposed (n=vcol, k=token)
          const int h = (col >> 6) - 16, c = blockIdx.y;
          const int vc = col & 63;
          const size_t u = (size_t)(h * 32 + c) * 640 +
              ((size_t)(vc >> 4) * 2 + wr) * 64 + (vc & 15) + (mb * 2 + (kg >> 1)) * 16;
          ushort4 rr;
          rr.x = f2bf(a[0]); rr.y = f2bf(a[1]); rr.z = f2bf(a[2]); rr.w = f2bf(a[3]);
          *(ushort4*)&vT_pk[u * 8 + (kg & 1) * 4] = rr;
        }
      } else {
        const float bv = BIAS ? bias[col] : 0.f;
#pragma unroll
        for (int r = 0; r < 4; ++r)
          Cf[(size_t)(m0 + mb * 16 + kg * 4 + r) * ldc + col] = a[r] + bv;
      }
    }
  }
}

// ============ proj (MFMA + elu+1) fused with per-chunk K^T V'' sums ============
// grid (NCHUNK, 2 src, NH), 4 waves. Block = one chunk (64 tokens) x 128 features.
// src==1 blocks additionally compute kvsum[h][c] = k_proj^T @ V'' via LDS transpose.
__global__ __launch_bounds__(256) void proj_sums(
    const unsigned short* __restrict__ qkv_pk, const unsigned short* __restrict__ projpk,
    const unsigned short* __restrict__ vT_pk,
    unsigned short* __restrict__ q_pk, unsigned short* __restrict__ k_pk,
    float* __restrict__ kvsum)
{
  __shared__ unsigned short kT[8192];   // PK(128,64) = 1024 units, 16 KB
  const int lane = threadIdx.x & 63, w = threadIdx.x >> 6;
  const int wr = w & 1, wc = w >> 1;
  const int c = blockIdx.x, src = blockIdx.y, h = blockIdx.z;
  const int r16 = lane & 15, kg = lane >> 4;
  const unsigned short* abase = qkv_pk + (size_t)(src * 8 + h) * 16384 * 8;
  const unsigned short* bbase = projpk + (size_t)h * 1024 * 8 + (size_t)lane * 8;
  f32x4 acc[2][4] = {};
#pragma unroll
  for (int s = 0; s < 2; ++s) {
#pragma unroll
    for (int mb = 0; mb < 2; ++mb) {
      const bf16x8 af = *(const bf16x8*)(abase +
          (((size_t)(c * 4 + wr * 2 + mb) * 2 + s) * 64 + lane) * 8);
#pragma unroll
      for (int nb = 0; nb < 4; ++nb) {
        const bf16x8 bv = *(const bf16x8*)(bbase + (size_t)((wc * 4 + nb) * 2 + s) * 512);
        acc[mb][nb] = __builtin_amdgcn_mfma_f32_16x16x32_bf16(af, bv, acc[mb][nb], 0, 0, 0);
      }
    }
  }
  // epilogue: elu+1, write packed q_pk/k_pk (+ LDS kT for the sums phase)
  unsigned short* dst = (src ? k_pk : q_pk) + (size_t)h * 32768 * 8;
#pragma unroll
  for (int mb = 0; mb < 2; ++mb) {
#pragma unroll
    for (int nb = 0; nb < 4; ++nb) {
      unsigned short vb[4];
#pragma unroll
      for (int r = 0; r < 4; ++r) {
        const float v = acc[mb][nb][r];
        vb[r] = f2bf(v > 0.f ? v + 1.f : expf(v));
      }
      // q_pk/k_pk PK(2048,128): f = wc*64 + nb*16 + r16
      const size_t base = ((size_t)(c * 4 + wr * 2 + mb) * 4 + wc * 2 + (nb >> 1)) * 64 +
                          ((nb & 1) * 2 + (r16 >> 3)) * 16;
      const int elem = r16 & 7;
#pragma unroll
      for (int r = 0; r < 4; ++r)
        dst[(base + kg * 4 + r) * 8 + elem] = vb[r];
      if (src == 1) {
        // kT LDS PK(128,64): m=f, k=token lt = wr*32+mb*16+kg*4+r
        const size_t u = ((size_t)(wc * 4 + nb) * 2 + wr) * 64 + r16 + (mb * 2 + (kg >> 1)) * 16;
        *(ushort4*)&kT[u * 8 + (kg & 1) * 4] = *(ushort4*)&vb[0];
      }
    }
  }
  if (src == 1) {
    __syncthreads();
    // kvsum = kT^T-weighted GEMM: M=128 (f), N=80, K=64 tokens
    const int wr2 = w >> 1, wc2 = w & 1;
    const int nnt = wc2 ? 2 : 3;
    const int ntb = wc2 ? 3 : 0;
    const unsigned short* vb_base = vT_pk + (size_t)(h * 32 + c) * 640 * 8;
    f32x4 acc2[4][3] = {};
#pragma unroll
    for (int ks = 0; ks < 2; ++ks) {
      bf16x8 bfr[3];
      for (int j = 0; j < 3; ++j)
        if (j < nnt)
          bfr[j] = *(const bf16x8*)(vb_base + (((size_t)(ntb + j) * 2 + ks) * 64 + lane) * 8);
#pragma unroll
      for (int amb = 0; amb < 4; ++amb) {
        const bf16x8 af = *(const bf16x8*)&kT[((((size_t)(wr2 * 4 + amb)) * 2 + ks) * 64 + lane) * 8];
        for (int j = 0; j < 3; ++j)
          if (j < nnt)
            acc2[amb][j] = __builtin_amdgcn_mfma_f32_16x16x32_bf16(af, bfr[j], acc2[amb][j], 0, 0, 0);
      }
    }
    float* outp = kvsum + (size_t)(h * 32 + c) * 128 * 80;
#pragma unroll
    for (int amb = 0; amb < 4; ++amb)
      for (int j = 0; j < 3; ++j)
        if (j < nnt) {
          const int colv = (ntb + j) * 16 + r16;
#pragma unroll
          for (int r = 0; r < 4; ++r)
            outp[(size_t)(wr2 * 64 + amb * 16 + kg * 4 + r) * 80 + colv] = acc2[amb][j][r];
        }
  }
}

// ============ exclusive prefix over chunks: kvsum f32 -> kvpre_pk bf16 ============
// thread = (h, f8, vc): 8 running sums over f = f8*8..+7, column vc.
__global__ __launch_bounds__(256) void chunk_scan(
    const float* __restrict__ kvsum, unsigned short* __restrict__ kvpre_pk)
{
  const int tid = blockIdx.x * 256 + threadIdx.x;
  if (tid >= 10240) return;
  const int h = tid / 1280, rem = tid % 1280;
  const int f8 = rem / 80, vc = rem % 80;
  float run[8] = {};
  const size_t u = ((size_t)(vc >> 4) * 4 + (f8 >> 2)) * 64 + (vc & 15) + (f8 & 3) * 16;
  for (int c = 0; c < NCHUNK; ++c) {
    unsigned short o[8];
#pragma unroll
    for (int e = 0; e < 8; ++e) o[e] = f2bf(run[e]);
    unsigned short* dst = kvpre_pk + ((size_t)(h * 32 + c) * 1280 + u) * 8;
    *(ushort4*)&dst[0] = *(ushort4*)&o[0];
    *(ushort4*)&dst[4] = *(ushort4*)&o[4];
    const float* srcp = kvsum + ((size_t)(h * 32 + c) * 128 + f8 * 8) * 80 + vc;
#pragma unroll
    for (int e = 0; e < 8; ++e) run[e] += srcp[(size_t)e * 80];
  }
}

// ============ chunk attention: S=QK^T -> mask -> P; O = Q@KVpre'' + P@V'' ============
// col 64 of the combined accumulator IS the denominator. grid (NCHUNK, NH), 4 waves.
__global__ __launch_bounds__(256) void chunk_attn(
    const unsigned short* __restrict__ q_pk, const unsigned short* __restrict__ k_pk,
    const unsigned short* __restrict__ kvpre_pk, const unsigned short* __restrict__ vT_pk,
    unsigned short* __restrict__ attn_pk)
{
  __shared__ unsigned short P[4096];   // PK(64,64) = 512 units, 8 KB
  __shared__ float den[64];
  const int lane = threadIdx.x & 63, w = threadIdx.x >> 6;
  const int wr = w >> 1, wc = w & 1;
  const int c = blockIdx.x, h = blockIdx.y;
  const int r16 = lane & 15, kg = lane >> 4;
  const unsigned short* qb = q_pk + (size_t)h * 32768 * 8;
  const unsigned short* kb = k_pk + (size_t)h * 32768 * 8;
  // A fragments (rows wr*32..+31 of chunk c), kept for both S and inter GEMMs
  bf16x8 qa[2][4];
#pragma unroll
  for (int amb = 0; amb < 2; ++amb)
#pragma unroll
    for (int ks = 0; ks < 4; ++ks)
      qa[amb][ks] = *(const bf16x8*)(qb +
          (((size_t)(c * 4 + wr * 2 + amb) * 4 + ks) * 64 + lane) * 8);
  // ---- Phase A: S = Q K^T (32x32 per wave), mask, P -> LDS ----
  {
    f32x4 accS[2][2] = {};
#pragma unroll
    for (int ks = 0; ks < 4; ++ks) {
#pragma unroll
      for (int bnb = 0; bnb < 2; ++bnb) {
        const bf16x8 bf = *(const bf16x8*)(kb +
            (((size_t)(c * 4 + wc * 2 + bnb) * 4 + ks) * 64 + lane) * 8);
#pragma unroll
        for (int amb = 0; amb < 2; ++amb)
          accS[amb][bnb] = __builtin_amdgcn_mfma_f32_16x16x32_bf16(qa[amb][ks], bf, accS[amb][bnb], 0, 0, 0);
      }
    }
#pragma unroll
    for (int amb = 0; amb < 2; ++amb)
#pragma unroll
      for (int bnb = 0; bnb < 2; ++bnb) {
        const int ck = wc * 32 + bnb * 16 + r16;
        const size_t u = ((size_t)(wr * 2 + amb) * 2 + wc) * 64 + (bnb * 2 + (r16 >> 3)) * 16;
        const int elem = r16 & 7;
#pragma unroll
        for (int r = 0; r < 4; ++r) {
          const int rq = wr * 32 + amb * 16 + kg * 4 + r;
          P[(u + kg * 4 + r) * 8 + elem] = (ck <= rq) ? f2bf(accS[amb][bnb][r]) : (unsigned short)0;
        }
      }
  }
  __syncthreads();
  // ---- Phase B: O = Q @ KVpre'' + P @ V'' ----
  const int nnt = wc ? 2 : 3;
  const int ntb = wc ? 3 : 0;
  const unsigned short* kvp = kvpre_pk + (size_t)(h * 32 + c) * 1280 * 8;
  const unsigned short* vtb = vT_pk + (size_t)(h * 32 + c) * 640 * 8;
  f32x4 acc[2][3] = {};
#pragma unroll
  for (int ks = 0; ks < 4; ++ks) {
    bf16x8 bfr[3];
    for (int j = 0; j < 3; ++j)
      if (j < nnt)
        bfr[j] = *(const bf16x8*)(kvp + (((size_t)(ntb + j) * 4 + ks) * 64 + lane) * 8);
#pragma unroll
    for (int amb = 0; amb < 2; ++amb)
      for (int j = 0; j < 3; ++j)
        if (j < nnt)
          acc[amb][j] = __builtin_amdgcn_mfma_f32_16x16x32_bf16(qa[amb][ks], bfr[j], acc[amb][j], 0, 0, 0);
  }
#pragma unroll
  for (int ks = 0; ks < 2; ++ks) {
    bf16x8 bfr[3];
    for (int j = 0; j < 3; ++j)
      if (j < nnt)
        bfr[j] = *(const bf16x8*)(vtb + (((size_t)(ntb + j) * 2 + ks) * 64 + lane) * 8);
#pragma unroll
    for (int amb = 0; amb < 2; ++amb) {
      const bf16x8 pf = *(const bf16x8*)&P[((((size_t)(wr * 2 + amb)) * 2 + ks) * 64 + lane) * 8];
      for (int j = 0; j < 3; ++j)
        if (j < nnt)
          acc[amb][j] = __builtin_amdgcn_mfma_f32_16x16x32_bf16(pf, bfr[j], acc[amb][j], 0, 0, 0);
    }
  }
  // denominator = column 64 (n-tile 4, r16==0), held by wc==1, j==1
  if (wc == 1 && r16 == 0) {
#pragma unroll
    for (int amb = 0; amb < 2; ++amb)
#pragma unroll
      for (int r = 0; r < 4; ++r)
        den[wr * 32 + amb * 16 + kg * 4 + r] = acc[amb][1][r] + EPS_C;
  }
  __syncthreads();
  // normalize + store packed attn (cols h*64 + vc, vc<64)
#pragma unroll
  for (int amb = 0; amb < 2; ++amb) {
    for (int j = 0; j < 3; ++j) {
      const int nt = ntb + j;
      if (nt >= 4 || j >= nnt) continue;
      const int acol = h * 64 + nt * 16 + r16;
      const size_t base = ((size_t)(c * 4 + wr * 2 + amb) * 16 + (acol >> 5)) * 64 +
                          ((nt * 2 + (r16 >> 3)) & 3) * 16;
      const int elem = acol & 7;
#pragma unroll
      for (int r = 0; r < 4; ++r) {
        const float dinv = 1.0f / den[wr * 32 + amb * 16 + kg * 4 + r];
        attn_pk[(base + kg * 4 + r) * 8 + elem] = f2bf(acc[amb][j][r] * dinv);
      }
    }
  }
}

extern "C" void kernel_launch(void* const* d_in, const int* in_sizes, int n_in,
                              void* d_out, int out_size, void* d_ws, size_t ws_size,
                              hipStream_t stream) {
  const float* x     = (const float*)d_in[0];
  const float* proj  = (const float*)d_in[1];
  const float* W_qkv = (const float*)d_in[2];
  const float* W_out = (const float*)d_in[3];
  const float* b_out = (const float*)d_in[4];
  float* out = (float*)d_out;

  float* kvsum = (float*)d_ws;                                   // 2,621,440 f
  unsigned short* xpk     = (unsigned short*)(kvsum + 2621440);  // 1,048,576 us
  unsigned short* wqkvpk  = xpk + 1048576;                       //   786,432
  unsigned short* woutpk  = wqkvpk + 786432;                     //   262,144
  unsigned short* projpk  = woutpk + 262144;                     //    65,536
  unsigned short* qkv_pk  = projpk + 65536;                      // 2,097,152
  unsigned short* q_pk    = qkv_pk + 2097152;                    // 2,097,152
  unsigned short* k_pk    = q_pk + 2097152;                      // 2,097,152
  unsigned short* vT_pk   = k_pk + 2097152;                      // 1,310,720
  unsigned short* kvpre_pk= vT_pk + 1310720;                     // 2,621,440
  unsigned short* attn_pk = kvpre_pk + 2621440;                  // 1,048,576
  // total ~37.5 MB

  // 0) pack inputs + constant V'' ones-tile
  pack_all<<<dim3(512, 5), 256, 0, stream>>>(x, W_qkv, W_out, proj,
                                             xpk, wqkvpk, woutpk, projpk, vT_pk);
  // 1) qkv GEMM -> Q,K packed per (src,h); V transposed-packed per (h,c)
  gemm_pk<false, 1><<<dim3(QKV_LD / 64, NTOK / 64), 256, 0, stream>>>(
      xpk, wqkvpk, nullptr, nullptr, qkv_pk, vT_pk, DMODEL, 0);
  // 2) proj + elu+1 -> q_pk/k_pk; fused per-chunk kvsum = k_proj^T @ V''
  proj_sums<<<dim3(NCHUNK, 2, NH), 256, 0, stream>>>(
      qkv_pk, projpk, vT_pk, q_pk, k_pk, kvsum);
  // 3) exclusive chunk prefix -> kvpre packed bf16 (col 64 = kpre)
  chunk_scan<<<dim3(40), 256, 0, stream>>>(kvsum, kvpre_pk);
  // 4) chunk attention -> attn packed bf16
  chunk_attn<<<dim3(NCHUNK, NH), 256, 0, stream>>>(
      q_pk, k_pk, kvpre_pk, vT_pk, attn_pk);
  // 5) out = attn @ W_out + b_out
  gemm_pk<true, 0><<<dim3(DMODEL / 64, NTOK / 64), 256, 0, stream>>>(
      attn_pk, woutpk, b_out, out, nullptr, nullptr, DMODEL, DMODEL);
}

// Round 6
// 52.453 us; speedup vs baseline: 2.6276x; 1.0640x over previous
//
#include <hip/hip_runtime.h>
#include <math.h>

#define NTOK 2048
#define DMODEL 512
#define NH 8
#define HD 64
#define NF 128
#define QKV_LD 1536
#define CHUNK 64
#define NCHUNK 32
#define EPS_C 1e-8f

typedef __bf16 bf16x8 __attribute__((ext_vector_type(8)));
typedef float f32x4 __attribute__((ext_vector_type(4)));

__device__ inline unsigned short f2bf(float f) {
  union { float f; unsigned u; } v; v.f = f;
  unsigned r = v.u + 0x7FFF + ((v.u >> 16) & 1);   // RNE
  return (unsigned short)(r >> 16);
}

// Packed fragment layout PK(M,K) for MFMA operand (A: [m][k]; B: [n][k]):
//   unit(m,k)  = ((m>>4)*(K>>5) + (k>>5))*64 + (m&15) + ((k>>3)&3)*16
//   ushort idx = unit*8 + (k&7)

// ============ pack_all ============
// jobs 0-3: inputs -> packed bf16. job 4: vT_pk n-tile 4 (col 64 = ones).
__global__ __launch_bounds__(256) void pack_all(
    const float* __restrict__ x, const float* __restrict__ W_qkv,
    const float* __restrict__ W_out, const float* __restrict__ proj,
    unsigned short* __restrict__ xpk, unsigned short* __restrict__ wqkvpk,
    unsigned short* __restrict__ woutpk, unsigned short* __restrict__ projpk,
    unsigned short* __restrict__ vT_pk)
{
  const int tid = blockIdx.x * 256 + threadIdx.x;
  const int job = blockIdx.y;
  unsigned short o[8];
  if (job == 0) {
    if (tid >= 131072) return;
    const int lane = tid & 63, blk = tid >> 6;
    const int bk = blk & 15, bm = blk >> 4;
    const int m = bm * 16 + (lane & 15), k = bk * 32 + (lane >> 4) * 8;
    const float4 v0 = *(const float4*)&x[(size_t)m * 512 + k];
    const float4 v1 = *(const float4*)&x[(size_t)m * 512 + k + 4];
    o[0] = f2bf(v0.x); o[1] = f2bf(v0.y); o[2] = f2bf(v0.z); o[3] = f2bf(v0.w);
    o[4] = f2bf(v1.x); o[5] = f2bf(v1.y); o[6] = f2bf(v1.z); o[7] = f2bf(v1.w);
    *(ushort4*)&xpk[(size_t)tid * 8]     = *(ushort4*)&o[0];
    *(ushort4*)&xpk[(size_t)tid * 8 + 4] = *(ushort4*)&o[4];
  } else if (job == 1) {
    if (tid >= 98304) return;
    const int lane = tid & 63, blk = tid >> 6;
    const int bk = blk & 15, bn = blk >> 4;
    const int n = bn * 16 + (lane & 15), k = bk * 32 + (lane >> 4) * 8;
#pragma unroll
    for (int e = 0; e < 8; ++e) o[e] = f2bf(W_qkv[(size_t)(k + e) * QKV_LD + n]);
    *(ushort4*)&wqkvpk[(size_t)tid * 8]     = *(ushort4*)&o[0];
    *(ushort4*)&wqkvpk[(size_t)tid * 8 + 4] = *(ushort4*)&o[4];
  } else if (job == 2) {
    if (tid >= 32768) return;
    const int lane = tid & 63, blk = tid >> 6;
    const int bk = blk & 15, bn = blk >> 4;
    const int n = bn * 16 + (lane & 15), k = bk * 32 + (lane >> 4) * 8;
#pragma unroll
    for (int e = 0; e < 8; ++e) o[e] = f2bf(W_out[(size_t)(k + e) * DMODEL + n]);
    *(ushort4*)&woutpk[(size_t)tid * 8]     = *(ushort4*)&o[0];
    *(ushort4*)&woutpk[(size_t)tid * 8 + 4] = *(ushort4*)&o[4];
  } else if (job == 3) {
    if (tid >= 8192) return;
    const int lane = tid & 63, blk = (tid >> 6) & 15, h = tid >> 10;
    const int bk = blk & 1, bn = blk >> 1;
    const int n = bn * 16 + (lane & 15), k = bk * 32 + (lane >> 4) * 8;
#pragma unroll
    for (int e = 0; e < 8; ++e) o[e] = f2bf(proj[(size_t)h * HD * NF + (size_t)(k + e) * NF + n]);
    *(ushort4*)&projpk[(size_t)tid * 8]     = *(ushort4*)&o[0];
    *(ushort4*)&projpk[(size_t)tid * 8 + 4] = *(ushort4*)&o[4];
  } else {
    if (tid >= 32768) return;                       // 256 (h,c) x 2 kt x 64 lanes
    const int hc = tid >> 7, kt = (tid >> 6) & 1, lane = tid & 63;
    const unsigned short val = ((lane & 15) == 0) ? (unsigned short)0x3F80 : (unsigned short)0;
    const size_t u = (size_t)hc * 640 + (4 * 2 + kt) * 64 + lane;
#pragma unroll
    for (int e = 0; e < 8; ++e) o[e] = val;
    *(ushort4*)&vT_pk[u * 8]     = *(ushort4*)&o[0];
    *(ushort4*)&vT_pk[u * 8 + 4] = *(ushort4*)&o[4];
  }
}

// ============ fused qkv GEMM + proj + elu+1 ============
// grid (24, 32): blockIdx.x = 64-col tile of qkv (0-7 Q, 8-15 K, 16-23 V),
// blockIdx.y = chunk (64 tokens). Q/K blocks: main GEMM -> LDS (packed) ->
// proj MFMA -> elu+1 -> q_pk/k_pk (+ kT_pk for K). V blocks -> vT_pk.
__global__ __launch_bounds__(256) void qkv_proj(
    const unsigned short* __restrict__ Apk, const unsigned short* __restrict__ Bpk,
    const unsigned short* __restrict__ projpk,
    unsigned short* __restrict__ q_pk, unsigned short* __restrict__ k_pk,
    unsigned short* __restrict__ kT_pk, unsigned short* __restrict__ vT_pk)
{
  __shared__ unsigned short QK[4096];   // PK(64,64), 8 KB
  const int lane = threadIdx.x & 63, w = threadIdx.x >> 6;
  const int wr = w >> 1, wc = w & 1;
  const int c = blockIdx.y;
  const int m0 = c * 64 + wr * 32;
  const int n0 = blockIdx.x * 64 + wc * 32;
  const unsigned short* a0 = Apk + ((size_t)(m0 >> 4) * 16 * 64 + lane) * 8;
  const unsigned short* a1 = a0 + (size_t)16 * 512;
  const unsigned short* b0 = Bpk + ((size_t)(n0 >> 4) * 16 * 64 + lane) * 8;
  const unsigned short* b1 = b0 + (size_t)16 * 512;
  f32x4 acc00 = {0.f, 0.f, 0.f, 0.f}, acc01 = acc00, acc10 = acc00, acc11 = acc00;
#pragma unroll 4
  for (int s = 0; s < 16; ++s) {
    const bf16x8 af0 = *(const bf16x8*)(a0 + (size_t)s * 512);
    const bf16x8 af1 = *(const bf16x8*)(a1 + (size_t)s * 512);
    const bf16x8 bv0 = *(const bf16x8*)(b0 + (size_t)s * 512);
    const bf16x8 bv1 = *(const bf16x8*)(b1 + (size_t)s * 512);
    acc00 = __builtin_amdgcn_mfma_f32_16x16x32_bf16(af0, bv0, acc00, 0, 0, 0);
    acc01 = __builtin_amdgcn_mfma_f32_16x16x32_bf16(af0, bv1, acc01, 0, 0, 0);
    acc10 = __builtin_amdgcn_mfma_f32_16x16x32_bf16(af1, bv0, acc10, 0, 0, 0);
    acc11 = __builtin_amdgcn_mfma_f32_16x16x32_bf16(af1, bv1, acc11, 0, 0, 0);
  }
  const int r16 = lane & 15, kg = lane >> 4;
  if (blockIdx.x < 16) {
    const int src = blockIdx.x >> 3, h = blockIdx.x & 7;
    // ---- qkv tile -> LDS PK(64,64) ----
#pragma unroll
    for (int mb = 0; mb < 2; ++mb) {
#pragma unroll
      for (int nb = 0; nb < 2; ++nb) {
        const f32x4 a = mb == 0 ? (nb == 0 ? acc00 : acc01) : (nb == 0 ? acc10 : acc11);
        const size_t u = ((size_t)(wr * 2 + mb) * 2 + wc) * 64 +
                         (nb * 2 + (r16 >> 3)) * 16 + kg * 4;
        const int elem = r16 & 7;
#pragma unroll
        for (int r = 0; r < 4; ++r)
          QK[(u + r) * 8 + elem] = f2bf(a[r]);
      }
    }
    __syncthreads();
    // ---- proj GEMM: 64 tokens x 128 features x K=64, + elu+1 ----
    const unsigned short* bbase = projpk + (size_t)h * 8192 + (size_t)lane * 8;
    f32x4 p[2][4] = {};
#pragma unroll
    for (int s = 0; s < 2; ++s) {
#pragma unroll
      for (int mb = 0; mb < 2; ++mb) {
        const bf16x8 af = *(const bf16x8*)&QK[((((size_t)(wr * 2 + mb)) * 2 + s) * 64 + lane) * 8];
#pragma unroll
        for (int nb = 0; nb < 4; ++nb) {
          const bf16x8 bv = *(const bf16x8*)(bbase + (size_t)((wc * 4 + nb) * 2 + s) * 512);
          p[mb][nb] = __builtin_amdgcn_mfma_f32_16x16x32_bf16(af, bv, p[mb][nb], 0, 0, 0);
        }
      }
    }
    unsigned short* dst = (src ? k_pk : q_pk) + (size_t)h * 262144;
#pragma unroll
    for (int mb = 0; mb < 2; ++mb) {
#pragma unroll
      for (int nb = 0; nb < 4; ++nb) {
        unsigned short vb[4];
#pragma unroll
        for (int r = 0; r < 4; ++r) {
          const float v = p[mb][nb][r];
          vb[r] = f2bf(v > 0.f ? v + 1.f : expf(v));
        }
        const size_t base = ((size_t)(c * 4 + wr * 2 + mb) * 4 + wc * 2 + (nb >> 1)) * 64 +
                            ((nb & 1) * 2 + (r16 >> 3)) * 16;
        const int elem = r16 & 7;
#pragma unroll
        for (int r = 0; r < 4; ++r)
          dst[(base + kg * 4 + r) * 8 + elem] = vb[r];
        if (src == 1) {
          // transposed copy for the sums GEMM: kT PK(128,64) per (h,c)
          const size_t u = (size_t)(h * 32 + c) * 1024 +
              ((size_t)(wc * 4 + nb) * 2 + wr) * 64 + r16 + (mb * 2 + (kg >> 1)) * 16;
          *(ushort4*)&kT_pk[u * 8 + (kg & 1) * 4] = *(ushort4*)&vb[0];
        }
      }
    }
  } else {
    // ---- V -> vT_pk PK(80,64) per (h,c), transposed ----
    const int h = blockIdx.x - 16;
#pragma unroll
    for (int mb = 0; mb < 2; ++mb) {
#pragma unroll
      for (int nb = 0; nb < 2; ++nb) {
        const f32x4 a = mb == 0 ? (nb == 0 ? acc00 : acc01) : (nb == 0 ? acc10 : acc11);
        const int vc = wc * 32 + nb * 16 + r16;
        const size_t u = (size_t)(h * 32 + c) * 640 +
            ((size_t)(vc >> 4) * 2 + wr) * 64 + (vc & 15) + (mb * 2 + (kg >> 1)) * 16;
        ushort4 rr;
        rr.x = f2bf(a[0]); rr.y = f2bf(a[1]); rr.z = f2bf(a[2]); rr.w = f2bf(a[3]);
        *(ushort4*)&vT_pk[u * 8 + (kg & 1) * 4] = rr;
      }
    }
  }
}

// ============ fused chunk-sums + exclusive scan ============
// grid (5 vtiles, NH), 4 waves; wave w owns features w*32..+31, block owns
// V''-cols vt*16..+15. The MFMA accumulator IS the running prefix:
// for c: emit acc (= sum of chunks < c) -> kvpre_pk[c]; acc += kT(c)@V''(c).
__global__ __launch_bounds__(256) void sums_scan(
    const unsigned short* __restrict__ kT_pk, const unsigned short* __restrict__ vT_pk,
    unsigned short* __restrict__ kvpre_pk)
{
  const int lane = threadIdx.x & 63, w = threadIdx.x >> 6;
  const int vt = blockIdx.x, h = blockIdx.y;
  const int r16 = lane & 15, kg = lane >> 4;
  f32x4 acc[2] = {};
  for (int c = 0; c < NCHUNK; ++c) {
    unsigned short* dst = kvpre_pk + (size_t)(h * 32 + c) * 1280 * 8;
#pragma unroll
    for (int mb = 0; mb < 2; ++mb) {
      unsigned short vb[4];
#pragma unroll
      for (int r = 0; r < 4; ++r) vb[r] = f2bf(acc[mb][r]);
      const size_t u = (size_t)(vt * 4 + w) * 64 + r16 + (mb * 2 + (kg >> 1)) * 16;
      *(ushort4*)&dst[u * 8 + (kg & 1) * 4] = *(ushort4*)&vb[0];
    }
    const unsigned short* kb = kT_pk + (size_t)(h * 32 + c) * 1024 * 8;
    const unsigned short* vb_ = vT_pk + (size_t)(h * 32 + c) * 640 * 8;
#pragma unroll
    for (int s = 0; s < 2; ++s) {
      const bf16x8 bf = *(const bf16x8*)(vb_ + (((size_t)vt * 2 + s) * 64 + lane) * 8);
#pragma unroll
      for (int mb = 0; mb < 2; ++mb) {
        const bf16x8 af = *(const bf16x8*)(kb + ((((size_t)(w * 2 + mb)) * 2 + s) * 64 + lane) * 8);
        acc[mb] = __builtin_amdgcn_mfma_f32_16x16x32_bf16(af, bf, acc[mb], 0, 0, 0);
      }
    }
  }
}

// ============ packed bf16 MFMA GEMM (final projection) ============
__global__ __launch_bounds__(256) void gemm_out(
    const unsigned short* __restrict__ Apk, const unsigned short* __restrict__ Bpk,
    const float* __restrict__ bias, float* __restrict__ Cf, int K, int ldc)
{
  const int lane = threadIdx.x & 63, w = threadIdx.x >> 6;
  const int wr = w >> 1, wc = w & 1;
  const int m0 = blockIdx.y * 64 + wr * 32;
  const int n0 = blockIdx.x * 64 + wc * 32;
  const int ks = K >> 5;
  const unsigned short* a0 = Apk + ((size_t)(m0 >> 4) * ks * 64 + lane) * 8;
  const unsigned short* a1 = a0 + (size_t)ks * 512;
  const unsigned short* b0 = Bpk + ((size_t)(n0 >> 4) * ks * 64 + lane) * 8;
  const unsigned short* b1 = b0 + (size_t)ks * 512;
  f32x4 acc00 = {0.f, 0.f, 0.f, 0.f}, acc01 = acc00, acc10 = acc00, acc11 = acc00;
#pragma unroll 4
  for (int s = 0; s < ks; ++s) {
    const bf16x8 af0 = *(const bf16x8*)(a0 + (size_t)s * 512);
    const bf16x8 af1 = *(const bf16x8*)(a1 + (size_t)s * 512);
    const bf16x8 bv0 = *(const bf16x8*)(b0 + (size_t)s * 512);
    const bf16x8 bv1 = *(const bf16x8*)(b1 + (size_t)s * 512);
    acc00 = __builtin_amdgcn_mfma_f32_16x16x32_bf16(af0, bv0, acc00, 0, 0, 0);
    acc01 = __builtin_amdgcn_mfma_f32_16x16x32_bf16(af0, bv1, acc01, 0, 0, 0);
    acc10 = __builtin_amdgcn_mfma_f32_16x16x32_bf16(af1, bv0, acc10, 0, 0, 0);
    acc11 = __builtin_amdgcn_mfma_f32_16x16x32_bf16(af1, bv1, acc11, 0, 0, 0);
  }
  const int r16 = lane & 15, kg = lane >> 4;
#pragma unroll
  for (int mb = 0; mb < 2; ++mb) {
#pragma unroll
    for (int nb = 0; nb < 2; ++nb) {
      const f32x4 a = mb == 0 ? (nb == 0 ? acc00 : acc01) : (nb == 0 ? acc10 : acc11);
      const int col = n0 + nb * 16 + r16;
      const float bv = bias[col];
#pragma unroll
      for (int r = 0; r < 4; ++r)
        Cf[(size_t)(m0 + mb * 16 + kg * 4 + r) * ldc + col] = a[r] + bv;
    }
  }
}

// ============ chunk attention: S=QK^T -> mask -> P; O = Q@KVpre'' + P@V'' ============
// col 64 of the combined accumulator IS the denominator. grid (NCHUNK, NH), 4 waves.
__global__ __launch_bounds__(256) void chunk_attn(
    const unsigned short* __restrict__ q_pk, const unsigned short* __restrict__ k_pk,
    const unsigned short* __restrict__ kvpre_pk, const unsigned short* __restrict__ vT_pk,
    unsigned short* __restrict__ attn_pk)
{
  __shared__ unsigned short P[4096];   // PK(64,64) = 512 units, 8 KB
  __shared__ float den[64];
  const int lane = threadIdx.x & 63, w = threadIdx.x >> 6;
  const int wr = w >> 1, wc = w & 1;
  const int c = blockIdx.x, h = blockIdx.y;
  const int r16 = lane & 15, kg = lane >> 4;
  const unsigned short* qb = q_pk + (size_t)h * 262144;
  const unsigned short* kb = k_pk + (size_t)h * 262144;
  bf16x8 qa[2][4];
#pragma unroll
  for (int amb = 0; amb < 2; ++amb)
#pragma unroll
    for (int ks = 0; ks < 4; ++ks)
      qa[amb][ks] = *(const bf16x8*)(qb +
          (((size_t)(c * 4 + wr * 2 + amb) * 4 + ks) * 64 + lane) * 8);
  // ---- Phase A: S = Q K^T, causal mask, P -> LDS ----
  {
    f32x4 accS[2][2] = {};
#pragma unroll
    for (int ks = 0; ks < 4; ++ks) {
#pragma unroll
      for (int bnb = 0; bnb < 2; ++bnb) {
        const bf16x8 bf = *(const bf16x8*)(kb +
            (((size_t)(c * 4 + wc * 2 + bnb) * 4 + ks) * 64 + lane) * 8);
#pragma unroll
        for (int amb = 0; amb < 2; ++amb)
          accS[amb][bnb] = __builtin_amdgcn_mfma_f32_16x16x32_bf16(qa[amb][ks], bf, accS[amb][bnb], 0, 0, 0);
      }
    }
#pragma unroll
    for (int amb = 0; amb < 2; ++amb)
#pragma unroll
      for (int bnb = 0; bnb < 2; ++bnb) {
        const int ck = wc * 32 + bnb * 16 + r16;
        const size_t u = ((size_t)(wr * 2 + amb) * 2 + wc) * 64 + (bnb * 2 + (r16 >> 3)) * 16;
        const int elem = r16 & 7;
#pragma unroll
        for (int r = 0; r < 4; ++r) {
          const int rq = wr * 32 + amb * 16 + kg * 4 + r;
          P[(u + kg * 4 + r) * 8 + elem] = (ck <= rq) ? f2bf(accS[amb][bnb][r]) : (unsigned short)0;
        }
      }
  }
  __syncthreads();
  // ---- Phase B: O = Q @ KVpre'' + P @ V'' ----
  const int nnt = wc ? 2 : 3;
  const int ntb = wc ? 3 : 0;
  const unsigned short* kvp = kvpre_pk + (size_t)(h * 32 + c) * 1280 * 8;
  const unsigned short* vtb = vT_pk + (size_t)(h * 32 + c) * 640 * 8;
  f32x4 acc[2][3] = {};
#pragma unroll
  for (int ks = 0; ks < 4; ++ks) {
    bf16x8 bfr[3];
    for (int j = 0; j < 3; ++j)
      if (j < nnt)
        bfr[j] = *(const bf16x8*)(kvp + (((size_t)(ntb + j) * 4 + ks) * 64 + lane) * 8);
#pragma unroll
    for (int amb = 0; amb < 2; ++amb)
      for (int j = 0; j < 3; ++j)
        if (j < nnt)
          acc[amb][j] = __builtin_amdgcn_mfma_f32_16x16x32_bf16(qa[amb][ks], bfr[j], acc[amb][j], 0, 0, 0);
  }
#pragma unroll
  for (int ks = 0; ks < 2; ++ks) {
    bf16x8 bfr[3];
    for (int j = 0; j < 3; ++j)
      if (j < nnt)
        bfr[j] = *(const bf16x8*)(vtb + (((size_t)(ntb + j) * 2 + ks) * 64 + lane) * 8);
#pragma unroll
    for (int amb = 0; amb < 2; ++amb) {
      const bf16x8 pf = *(const bf16x8*)&P[((((size_t)(wr * 2 + amb)) * 2 + ks) * 64 + lane) * 8];
      for (int j = 0; j < 3; ++j)
        if (j < nnt)
          acc[amb][j] = __builtin_amdgcn_mfma_f32_16x16x32_bf16(pf, bfr[j], acc[amb][j], 0, 0, 0);
    }
  }
  if (wc == 1 && r16 == 0) {
#pragma unroll
    for (int amb = 0; amb < 2; ++amb)
#pragma unroll
      for (int r = 0; r < 4; ++r)
        den[wr * 32 + amb * 16 + kg * 4 + r] = acc[amb][1][r] + EPS_C;
  }
  __syncthreads();
#pragma unroll
  for (int amb = 0; amb < 2; ++amb) {
    for (int j = 0; j < 3; ++j) {
      const int nt = ntb + j;
      if (nt >= 4 || j >= nnt) continue;
      const int acol = h * 64 + nt * 16 + r16;
      const size_t base = ((size_t)(c * 4 + wr * 2 + amb) * 16 + (acol >> 5)) * 64 +
                          ((nt * 2 + (r16 >> 3)) & 3) * 16;
      const int elem = acol & 7;
#pragma unroll
      for (int r = 0; r < 4; ++r) {
        const float dinv = 1.0f / den[wr * 32 + amb * 16 + kg * 4 + r];
        attn_pk[(base + kg * 4 + r) * 8 + elem] = f2bf(acc[amb][j][r] * dinv);
      }
    }
  }
}

extern "C" void kernel_launch(void* const* d_in, const int* in_sizes, int n_in,
                              void* d_out, int out_size, void* d_ws, size_t ws_size,
                              hipStream_t stream) {
  const float* x     = (const float*)d_in[0];
  const float* proj  = (const float*)d_in[1];
  const float* W_qkv = (const float*)d_in[2];
  const float* W_out = (const float*)d_in[3];
  const float* b_out = (const float*)d_in[4];
  float* out = (float*)d_out;

  unsigned short* xpk      = (unsigned short*)d_ws;          // 1,048,576 us
  unsigned short* wqkvpk   = xpk + 1048576;                  //   786,432
  unsigned short* woutpk   = wqkvpk + 786432;                //   262,144
  unsigned short* projpk   = woutpk + 262144;                //    65,536
  unsigned short* q_pk     = projpk + 65536;                 // 2,097,152
  unsigned short* k_pk     = q_pk + 2097152;                 // 2,097,152
  unsigned short* kT_pk    = k_pk + 2097152;                 // 2,097,152
  unsigned short* vT_pk    = kT_pk + 2097152;                // 1,310,720
  unsigned short* kvpre_pk = vT_pk + 1310720;                // 2,621,440
  unsigned short* attn_pk  = kvpre_pk + 2621440;             // 1,048,576
  // total 13,434,880 ushorts ~ 26.9 MB

  // 0) pack inputs + constant V'' ones-tile
  pack_all<<<dim3(512, 5), 256, 0, stream>>>(x, W_qkv, W_out, proj,
                                             xpk, wqkvpk, woutpk, projpk, vT_pk);
  // 1) fused qkv GEMM + proj + elu -> q_pk, k_pk, kT_pk, vT_pk
  qkv_proj<<<dim3(QKV_LD / 64, NTOK / 64), 256, 0, stream>>>(
      xpk, wqkvpk, projpk, q_pk, k_pk, kT_pk, vT_pk);
  // 2) fused chunk-sums + exclusive prefix -> kvpre_pk (col 64 = kpre)
  sums_scan<<<dim3(5, NH), 256, 0, stream>>>(kT_pk, vT_pk, kvpre_pk);
  // 3) chunk attention -> attn_pk
  chunk_attn<<<dim3(NCHUNK, NH), 256, 0, stream>>>(
      q_pk, k_pk, kvpre_pk, vT_pk, attn_pk);
  // 4) out = attn @ W_out + b_out
  gemm_out<<<dim3(DMODEL / 64, NTOK / 64), 256, 0, stream>>>(
      attn_pk, woutpk, b_out, out, DMODEL, DMODEL);
}